// Round 4
// baseline (440.389 us; speedup 1.0000x reference)
//
#include <hip/hip_runtime.h>

typedef __bf16 bf16x8 __attribute__((ext_vector_type(8)));
typedef unsigned short u16x8 __attribute__((ext_vector_type(8)));
typedef float f32x4 __attribute__((ext_vector_type(4)));
typedef unsigned short u16;

__device__ __forceinline__ float bf2f(u16 u) {
    union { unsigned int i; float f; } x; x.i = ((unsigned int)u) << 16; return x.f;
}
__device__ __forceinline__ u16 f2bf(float f) {
    union { float f; unsigned int i; } x; x.f = f;
    unsigned int u = x.i;
    unsigned int r = (u + 0x7FFFu + ((u >> 16) & 1u)) >> 16;
    return (u16)r;
}

#define GL16(g, l) __builtin_amdgcn_global_load_lds( \
    (__attribute__((address_space(1))) void*)(void*)(g), \
    (__attribute__((address_space(3))) void*)(void*)(l), 16, 0, 0)

// ---------------------------------------------------------------------------
// weights fp32 -> bf16
// ---------------------------------------------------------------------------
__global__ __launch_bounds__(256)
void cvt6_kernel(const float* __restrict__ s0, const float* __restrict__ s1,
                 const float* __restrict__ s2, const float* __restrict__ s3,
                 const float* __restrict__ s4, const float* __restrict__ s5,
                 u16* __restrict__ d0, u16* __restrict__ d1, u16* __restrict__ d2,
                 u16* __restrict__ d3, u16* __restrict__ d4, u16* __restrict__ d5)
{
    int b = blockIdx.x;
    const float* s; u16* d; int base;
    if (b < 512) {
        int t = b >> 7, lb = b & 127;
        s = (t == 0) ? s0 : (t == 1) ? s1 : (t == 2) ? s2 : s3;
        d = (t == 0) ? d0 : (t == 1) ? d1 : (t == 2) ? d2 : d3;
        base = lb * 2048;
    } else if (b < 1024) { s = s4; d = d4; base = (b - 512) * 2048; }
    else                 { s = s5; d = d5; base = (b - 1024) * 2048; }
    int i = base + threadIdx.x * 8;
    float4 a = *(const float4*)&s[i];
    float4 c = *(const float4*)&s[i + 4];
    u16x8 o;
    o[0] = f2bf(a.x); o[1] = f2bf(a.y); o[2] = f2bf(a.z); o[3] = f2bf(a.w);
    o[4] = f2bf(c.x); o[5] = f2bf(c.y); o[6] = f2bf(c.z); o[7] = f2bf(c.w);
    *(u16x8*)&d[i] = o;
}

// ---------------------------------------------------------------------------
// bias^T[j][i] = alpha*softmax_j(relu(E E^T))[i][j] + beta*lap[i][j] + mask
// TRANSPOSED output so flash_attn can float4-load along the q-row axis.
// ---------------------------------------------------------------------------
__global__ __launch_bounds__(256)
void bias_kernel(const float* __restrict__ E, const float* __restrict__ lap,
                 const float* __restrict__ alpha_p, const float* __restrict__ beta_p,
                 float* __restrict__ biasout)
{
    __shared__ float wred[8];
    int tid = threadIdx.x;
    int i = blockIdx.x;
    int lane = tid & 63, wave = tid >> 6;
    int j0 = tid, j1 = tid + 256;
    float s0 = 0.f, s1 = 0.f;
#pragma unroll
    for (int t4 = 0; t4 < 16; ++t4) {
        float4 a  = *(const float4*)&E[i * 64 + t4 * 4];
        float4 e0 = *(const float4*)&E[j0 * 64 + t4 * 4];
        float4 e1 = *(const float4*)&E[j1 * 64 + t4 * 4];
        s0 += a.x * e0.x + a.y * e0.y + a.z * e0.z + a.w * e0.w;
        s1 += a.x * e1.x + a.y * e1.y + a.z * e1.z + a.w * e1.w;
    }
    s0 = fmaxf(s0, 0.f); s1 = fmaxf(s1, 0.f);
    float m = fmaxf(s0, s1);
#pragma unroll
    for (int o = 32; o > 0; o >>= 1) m = fmaxf(m, __shfl_xor(m, o));
    if (lane == 0) wred[wave] = m;
    __syncthreads();
    m = fmaxf(fmaxf(wred[0], wred[1]), fmaxf(wred[2], wred[3]));
    float e0v = __expf(s0 - m), e1v = __expf(s1 - m);
    float sum = e0v + e1v;
#pragma unroll
    for (int o = 32; o > 0; o >>= 1) sum += __shfl_xor(sum, o);
    if (lane == 0) wred[4 + wave] = sum;
    __syncthreads();
    float inv = 1.f / (wred[4] + wred[5] + wred[6] + wred[7]);
    float alpha = alpha_p[0], beta = beta_p[0];
    float lv0 = lap[i * 512 + j0];
    float lv1 = lap[i * 512 + j1];
    // transposed store: biasT[key][query]
    biasout[j0 * 512 + i] = alpha * (e0v * inv) + beta * lv0 + (lv0 != 0.f ? 0.f : -1e9f);
    biasout[j1 * 512 + i] = alpha * (e1v * inv) + beta * lv1 + (lv1 != 0.f ? 0.f : -1e9f);
}

// ---------------------------------------------------------------------------
// LayerNorm D=512, fp32 in, bf16 out
// ---------------------------------------------------------------------------
__global__ __launch_bounds__(256)
void ln_kernel(const float* __restrict__ X, const float* __restrict__ G,
               const float* __restrict__ Bb, u16* __restrict__ Y)
{
    int row = blockIdx.x * 4 + (threadIdx.x >> 6);
    int lane = threadIdx.x & 63;
    const float* xr = X + (size_t)row * 512 + lane * 8;
    float4 a = *(const float4*)xr;
    float4 b = *(const float4*)(xr + 4);
    float v[8] = {a.x, a.y, a.z, a.w, b.x, b.y, b.z, b.w};
    float s = 0.f, ss = 0.f;
#pragma unroll
    for (int i = 0; i < 8; i++) { s += v[i]; ss += v[i] * v[i]; }
#pragma unroll
    for (int o = 32; o > 0; o >>= 1) { s += __shfl_xor(s, o); ss += __shfl_xor(ss, o); }
    float mu = s * (1.f / 512.f);
    float var = ss * (1.f / 512.f) - mu * mu;
    float rstd = rsqrtf(var + 1e-5f);
    float4 g0 = *(const float4*)&G[lane * 8];
    float4 g1 = *(const float4*)&G[lane * 8 + 4];
    float4 b0 = *(const float4*)&Bb[lane * 8];
    float4 b1 = *(const float4*)&Bb[lane * 8 + 4];
    float gv[8] = {g0.x, g0.y, g0.z, g0.w, g1.x, g1.y, g1.z, g1.w};
    float bv[8] = {b0.x, b0.y, b0.z, b0.w, b1.x, b1.y, b1.z, b1.w};
    u16x8 out;
#pragma unroll
    for (int i = 0; i < 8; i++) out[i] = f2bf((v[i] - mu) * rstd * gv[i] + bv[i]);
    *(u16x8*)&Y[(size_t)row * 512 + lane * 8] = out;
}

// ---------------------------------------------------------------------------
// LDS GEMM (m97 pattern), 128x128 tile, XCD-swizzled, bf16 out (mode 0/1).
// Epilogue staged through LDS (stride 136) -> coalesced u16x8 global stores.
// ---------------------------------------------------------------------------
__global__ __launch_bounds__(256)
void gemm_bt(const u16* __restrict__ A, const u16* __restrict__ W,
             const float* __restrict__ bias,
             u16* __restrict__ Cb, int M, int Kd, int Nout, int mode)
{
    __shared__ __align__(16) char smem[128 * 136 * 2];   // 34 KB (>= lA+lB 16 KB)
    u16* lA = (u16*)smem;
    u16* lB = lA + 128 * 32;
    int tid = threadIdx.x;
    int lane = tid & 63, wave = tid >> 6;
    int wm = wave >> 1, wn = wave & 1;
    int bid = blockIdx.y * gridDim.x + blockIdx.x;
    int per = (gridDim.x * gridDim.y) >> 3;
    int lb  = (bid & 7) * per + (bid >> 3);
    int bx = lb % gridDim.x, by = lb / gridDim.x;
    int row0 = by * 128, col0 = bx * 128;
    int rl = lane & 15, kq = lane >> 4;
    f32x4 acc[4][4];
#pragma unroll
    for (int i = 0; i < 4; i++)
#pragma unroll
        for (int j = 0; j < 4; j++) acc[i][j] = (f32x4){0.f, 0.f, 0.f, 0.f};

    int c0 = tid,       sr0 = c0 >> 2, sc0 = (c0 & 3) * 8;
    int c1 = 256 + tid, sr1 = c1 >> 2, sc1 = (c1 & 3) * 8;
    const u16* Abase = A + (size_t)row0 * Kd;
    const u16* Wbase = W + (size_t)col0 * Kd;

    for (int k0 = 0; k0 < Kd; k0 += 32) {
        GL16(Abase + (size_t)sr0 * Kd + k0 + sc0, &lA[c0 * 8]);
        GL16(Abase + (size_t)sr1 * Kd + k0 + sc1, &lA[c1 * 8]);
        GL16(Wbase + (size_t)sr0 * Kd + k0 + sc0, &lB[c0 * 8]);
        GL16(Wbase + (size_t)sr1 * Kd + k0 + sc1, &lB[c1 * 8]);
        __syncthreads();
        bf16x8 af[4], bf[4];
#pragma unroll
        for (int i = 0; i < 4; i++) af[i] = *(const bf16x8*)&lA[(wm * 64 + i * 16 + rl) * 32 + kq * 8];
#pragma unroll
        for (int j = 0; j < 4; j++) bf[j] = *(const bf16x8*)&lB[(wn * 64 + j * 16 + rl) * 32 + kq * 8];
#pragma unroll
        for (int i = 0; i < 4; i++)
#pragma unroll
            for (int j = 0; j < 4; j++)
                acc[i][j] = __builtin_amdgcn_mfma_f32_16x16x32_bf16(af[i], bf[j], acc[i][j], 0, 0, 0);
        __syncthreads();
    }
    // epilogue: stage bf16 tile in LDS, then coalesced stores
    u16* lC = (u16*)smem;
#pragma unroll
    for (int j = 0; j < 4; j++) {
        int col = wn * 64 + j * 16 + rl;
        float bsv = bias[col0 + col];
#pragma unroll
        for (int i = 0; i < 4; i++) {
            int rb = wm * 64 + i * 16 + kq * 4;
#pragma unroll
            for (int r = 0; r < 4; r++) {
                float vo = acc[i][j][r] + bsv;
                if (mode == 1) vo = fmaxf(vo, 0.f);
                lC[(rb + r) * 136 + col] = f2bf(vo);
            }
        }
    }
    __syncthreads();
#pragma unroll
    for (int rep = 0; rep < 8; rep++) {
        int row = rep * 16 + (tid >> 4);
        int col8 = (tid & 15) * 8;
        *(u16x8*)&Cb[(size_t)(row0 + row) * Nout + col0 + col8] = *(const u16x8*)&lC[row * 136 + col8];
    }
}

// ---------------------------------------------------------------------------
// 128x128-tile LDS GEMM, fp32 out with residual, direct-scatter epilogue
// (m97 structure: 16 MFMA per 4 staging loads; replaces the 64x128 gemm_bt64).
// ---------------------------------------------------------------------------
__global__ __launch_bounds__(256)
void gemm128_res(const u16* __restrict__ A, const u16* __restrict__ W,
                 const float* __restrict__ bias, const float* __restrict__ resid,
                 float* __restrict__ Cf, int M, int Kd, int Nout)
{
    __shared__ __align__(16) u16 lA[128 * 32];
    __shared__ __align__(16) u16 lB[128 * 32];
    int tid = threadIdx.x;
    int lane = tid & 63, wave = tid >> 6;
    int wm = wave >> 1, wn = wave & 1;
    int bid = blockIdx.y * gridDim.x + blockIdx.x;
    int per = (gridDim.x * gridDim.y) >> 3;
    int lb  = (bid & 7) * per + (bid >> 3);
    int bx = lb % gridDim.x, by = lb / gridDim.x;
    int row0 = by * 128, col0 = bx * 128;
    int rl = lane & 15, kq = lane >> 4;
    f32x4 acc[4][4];
#pragma unroll
    for (int i = 0; i < 4; i++)
#pragma unroll
        for (int j = 0; j < 4; j++) acc[i][j] = (f32x4){0.f, 0.f, 0.f, 0.f};

    int c0 = tid,       sr0 = c0 >> 2, sc0 = (c0 & 3) * 8;
    int c1 = 256 + tid, sr1 = c1 >> 2, sc1 = (c1 & 3) * 8;
    const u16* Abase = A + (size_t)row0 * Kd;
    const u16* Wbase = W + (size_t)col0 * Kd;

    for (int k0 = 0; k0 < Kd; k0 += 32) {
        GL16(Abase + (size_t)sr0 * Kd + k0 + sc0, &lA[c0 * 8]);
        GL16(Abase + (size_t)sr1 * Kd + k0 + sc1, &lA[c1 * 8]);
        GL16(Wbase + (size_t)sr0 * Kd + k0 + sc0, &lB[c0 * 8]);
        GL16(Wbase + (size_t)sr1 * Kd + k0 + sc1, &lB[c1 * 8]);
        __syncthreads();
        bf16x8 af[2], bf[4];
        // NOTE: af sized [4] in gemm_bt; here full 4x4 too
        bf16x8 af4[4];
#pragma unroll
        for (int i = 0; i < 4; i++) af4[i] = *(const bf16x8*)&lA[(wm * 64 + i * 16 + rl) * 32 + kq * 8];
#pragma unroll
        for (int j = 0; j < 4; j++) bf[j] = *(const bf16x8*)&lB[(wn * 64 + j * 16 + rl) * 32 + kq * 8];
#pragma unroll
        for (int i = 0; i < 4; i++)
#pragma unroll
            for (int j = 0; j < 4; j++)
                acc[i][j] = __builtin_amdgcn_mfma_f32_16x16x32_bf16(af4[i], bf[j], acc[i][j], 0, 0, 0);
        __syncthreads();
        (void)af;
    }
    // direct f32 epilogue: per quarter-wave a 64B contiguous run -> coalesced
#pragma unroll
    for (int j = 0; j < 4; j++) {
        int col = col0 + wn * 64 + j * 16 + rl;
        float bsv = bias[col];
#pragma unroll
        for (int i = 0; i < 4; i++) {
            int rb = row0 + wm * 64 + i * 16 + kq * 4;
#pragma unroll
            for (int r = 0; r < 4; r++) {
                size_t idx = (size_t)(rb + r) * Nout + col;
                Cf[idx] = acc[i][j][r] + bsv + resid[idx];
            }
        }
    }
}

// ---------------------------------------------------------------------------
// fused QKV, XCD-swizzled, LDS-staged epilogue
// ---------------------------------------------------------------------------
__global__ __launch_bounds__(256)
void gemm_qkv(const u16* __restrict__ A,
              const u16* __restrict__ W0, const u16* __restrict__ W1, const u16* __restrict__ W2,
              const float* __restrict__ b0, const float* __restrict__ b1, const float* __restrict__ b2,
              u16* __restrict__ C0, u16* __restrict__ C1, u16* __restrict__ C2)
{
    __shared__ __align__(16) char smem[128 * 136 * 2];   // 34 KB
    u16* lA = (u16*)smem;
    u16* lB = lA + 128 * 32;
    const int Kd = 512, Nout = 512;
    int bid = blockIdx.y * gridDim.x + blockIdx.x;
    int per = (gridDim.x * gridDim.y) >> 3;       // 192
    int lb  = (bid & 7) * per + (bid >> 3);
    int rest = lb % 12, by = lb / 12;
    int sel = rest >> 2;
    const u16* W = (sel == 0) ? W0 : (sel == 1) ? W1 : W2;
    const float* bias = (sel == 0) ? b0 : (sel == 1) ? b1 : b2;
    u16* Cb = (sel == 0) ? C0 : (sel == 1) ? C1 : C2;
    int tid = threadIdx.x;
    int lane = tid & 63, wave = tid >> 6;
    int wm = wave >> 1, wn = wave & 1;
    int row0 = by * 128, col0 = (rest & 3) * 128;
    int rl = lane & 15, kq = lane >> 4;
    f32x4 acc[4][4];
#pragma unroll
    for (int i = 0; i < 4; i++)
#pragma unroll
        for (int j = 0; j < 4; j++) acc[i][j] = (f32x4){0.f, 0.f, 0.f, 0.f};
    int c0 = tid,       sr0 = c0 >> 2, sc0 = (c0 & 3) * 8;
    int c1 = 256 + tid, sr1 = c1 >> 2, sc1 = (c1 & 3) * 8;
    const u16* Abase = A + (size_t)row0 * Kd;
    const u16* Wbase = W + (size_t)col0 * Kd;
    for (int k0 = 0; k0 < Kd; k0 += 32) {
        GL16(Abase + (size_t)sr0 * Kd + k0 + sc0, &lA[c0 * 8]);
        GL16(Abase + (size_t)sr1 * Kd + k0 + sc1, &lA[c1 * 8]);
        GL16(Wbase + (size_t)sr0 * Kd + k0 + sc0, &lB[c0 * 8]);
        GL16(Wbase + (size_t)sr1 * Kd + k0 + sc1, &lB[c1 * 8]);
        __syncthreads();
        bf16x8 af[4], bf[4];
#pragma unroll
        for (int i = 0; i < 4; i++) af[i] = *(const bf16x8*)&lA[(wm * 64 + i * 16 + rl) * 32 + kq * 8];
#pragma unroll
        for (int j = 0; j < 4; j++) bf[j] = *(const bf16x8*)&lB[(wn * 64 + j * 16 + rl) * 32 + kq * 8];
#pragma unroll
        for (int i = 0; i < 4; i++)
#pragma unroll
            for (int j = 0; j < 4; j++)
                acc[i][j] = __builtin_amdgcn_mfma_f32_16x16x32_bf16(af[i], bf[j], acc[i][j], 0, 0, 0);
        __syncthreads();
    }
    u16* lC = (u16*)smem;
#pragma unroll
    for (int j = 0; j < 4; j++) {
        int col = wn * 64 + j * 16 + rl;
        float bsv = bias[col0 + col];
#pragma unroll
        for (int i = 0; i < 4; i++) {
            int rb = wm * 64 + i * 16 + kq * 4;
#pragma unroll
            for (int r = 0; r < 4; r++)
                lC[(rb + r) * 136 + col] = f2bf(acc[i][j][r] + bsv);
        }
    }
    __syncthreads();
#pragma unroll
    for (int rep = 0; rep < 8; rep++) {
        int row = rep * 16 + (tid >> 4);
        int col8 = (tid & 15) * 8;
        *(u16x8*)&Cb[(size_t)(row0 + row) * Nout + col0 + col8] = *(const u16x8*)&lC[row * 136 + col8];
    }
}

// ---------------------------------------------------------------------------
// flash attention v4 = v3 with the VGPR clamp removed.
// History: (256,3) -> VGPR 84, 220MB spill, 228us. (256,2) -> VGPR snapped to
// 128, ~8 regs spilled in K-loop, 121us. Plain (256): allocator free
// (~140-170 VGPR), zero scratch; LDS 54272 still allows 3 blocks/CU if <=168.
// ---------------------------------------------------------------------------
__global__ __launch_bounds__(256)
void flash_attn(const u16* __restrict__ Q, const u16* __restrict__ Km,
                const u16* __restrict__ V, const float* __restrict__ biasT,
                u16* __restrict__ O)
{
    __shared__ __align__(16) char smem[54272];
    u16* lPK      = (u16*)smem;                      // K-stage 128x64 (swz) / P 128x136 / O-stage
    u16* lQ       = (u16*)(smem + 34816);            // Q-stage 128x64 (swz), union with lVt
    unsigned* lVt = (unsigned*)(smem + 34816);       // V^T 64 x 64 dwords, 16B-slot swz
    float* red_m   = (float*)(smem + 51200);         // 256 f
    float* red_s   = red_m + 256;                    // 256 f
    float* alpha_s = red_s + 256;                    // 128 f
    float* l_s     = alpha_s + 128;                  // 128 f

    int tid = threadIdx.x, lane = tid & 63, wave = tid >> 6;
    int wm = wave >> 1, wn = wave & 1;
    int rl = lane & 15, kq = lane >> 4;
    int qt = blockIdx.x, h = blockIdx.y, bt = blockIdx.z;
    int qg0 = qt * 128;
    size_t hb = (size_t)bt * (512 * 512) + h * 64;
    const u16* Qbase = Q + hb + (size_t)qg0 * 512;
    const u16* Kb0   = Km + hb;
    const u16* Vb0   = V + hb;

    // stage Q: linear LDS dest, inverse-swizzled global source (rule #21)
#pragma unroll
    for (int rep = 0; rep < 4; ++rep) {
        int c = rep * 256 + tid;
        int qr = c >> 3, d0 = (((c & 7) ^ (qr & 7)) * 8);
        GL16(Qbase + (size_t)qr * 512 + d0, &lQ[c * 8]);
    }
    if (tid < 128) l_s[tid] = 0.f;
    __syncthreads();

    bf16x8 af[4][2];
#pragma unroll
    for (int i = 0; i < 4; i++) {
        int row = wm * 64 + i * 16 + rl;
#pragma unroll
        for (int s = 0; s < 2; s++) {
            int sl = (s * 4 + kq) ^ (row & 7);
            af[i][s] = *(const bf16x8*)&lQ[row * 64 + sl * 8];
        }
    }

    float m_reg[4][4];
    f32x4 o[4][2];
#pragma unroll
    for (int i = 0; i < 4; i++) {
#pragma unroll
        for (int r = 0; r < 4; r++) m_reg[i][r] = -3.0e38f;
#pragma unroll
        for (int jj = 0; jj < 2; jj++) o[i][jj] = (f32x4){0.f, 0.f, 0.f, 0.f};
    }

    for (int t = 0; t < 4; ++t) {
        int kv0 = t * 128;
        __syncthreads();                              // barrier 1: buffers reusable
        const u16* Kbase = Kb0 + (size_t)kv0 * 512;
#pragma unroll
        for (int rep = 0; rep < 4; ++rep) {
            int c = rep * 256 + tid;
            int kv = c >> 3, d0 = (((c & 7) ^ (kv & 7)) * 8);
            GL16(Kbase + (size_t)kv * 512 + d0, &lPK[c * 8]);
        }
        const u16* Vbase = Vb0 + (size_t)kv0 * 512;
#pragma unroll
        for (int rep = 0; rep < 2; ++rep) {
            int idx = rep * 256 + tid;
            int p = idx & 63, e0 = (idx >> 6) * 8;
            const u16* vp0 = Vbase + (size_t)(2 * p) * 512 + e0;
            u16x8 v0 = *(const u16x8*)vp0;
            u16x8 v1 = *(const u16x8*)(vp0 + 512);
#pragma unroll
            for (int u = 0; u < 8; ++u) {
                int row = e0 + u;
                int col = ((((p >> 2) ^ (row & 15)) << 2) | (p & 3));
                lVt[row * 64 + col] = (unsigned)v0[u] | ((unsigned)v1[u] << 16);
            }
        }
        __syncthreads();                              // barrier 2: tiles ready

        f32x4 acc[4][4];
#pragma unroll
        for (int j = 0; j < 4; ++j) {
            int row = wn * 64 + j * 16 + rl;
            int sl0 = kq ^ (row & 7), sl1 = (4 + kq) ^ (row & 7);
            bf16x8 bk0 = *(const bf16x8*)&lPK[row * 64 + sl0 * 8];
            bf16x8 bk1 = *(const bf16x8*)&lPK[row * 64 + sl1 * 8];
#pragma unroll
            for (int i = 0; i < 4; ++i) {
                acc[i][j] = __builtin_amdgcn_mfma_f32_16x16x32_bf16(af[i][0], bk0,
                            (f32x4){0.f, 0.f, 0.f, 0.f}, 0, 0, 0);
                acc[i][j] = __builtin_amdgcn_mfma_f32_16x16x32_bf16(af[i][1], bk1, acc[i][j], 0, 0, 0);
            }
        }
        // bias add: transposed table -> one float4 per (i,j)
#pragma unroll
        for (int j = 0; j < 4; ++j) {
            int colg = kv0 + wn * 64 + j * 16 + rl;
            const float* bp = biasT + (size_t)colg * 512 + qg0;
#pragma unroll
            for (int i = 0; i < 4; ++i) {
                float4 bv = *(const float4*)&bp[wm * 64 + i * 16 + kq * 4];
                float bvr[4] = {bv.x, bv.y, bv.z, bv.w};
#pragma unroll
                for (int r = 0; r < 4; ++r)
                    acc[i][j][r] = acc[i][j][r] * 0.125f + bvr[r];
            }
        }
        // row max (this wn half) -> red_m
#pragma unroll
        for (int i = 0; i < 4; ++i) {
            float mx[4];
#pragma unroll
            for (int r = 0; r < 4; ++r) {
                mx[r] = fmaxf(fmaxf(acc[i][0][r], acc[i][1][r]), fmaxf(acc[i][2][r], acc[i][3][r]));
#pragma unroll
                for (int off = 8; off > 0; off >>= 1) mx[r] = fmaxf(mx[r], __shfl_xor(mx[r], off));
            }
            if (rl == 0) {
                int rb = wm * 64 + i * 16 + kq * 4;
#pragma unroll
                for (int r = 0; r < 4; ++r) red_m[wn * 128 + rb + r] = mx[r];
            }
        }
        __syncthreads();                              // barrier 3: max exchange

#pragma unroll
        for (int i = 0; i < 4; ++i) {
            int rb = wm * 64 + i * 16 + kq * 4;
            float mn[4], al[4], sm[4];
#pragma unroll
            for (int r = 0; r < 4; ++r) {
                float pm = fmaxf(red_m[rb + r], red_m[128 + rb + r]);
                float mo = m_reg[i][r];
                mn[r] = fmaxf(mo, pm);
                al[r] = __expf(mo - mn[r]);
                m_reg[i][r] = mn[r];
                sm[r] = 0.f;
            }
            if (rl == 0 && wn == 0) {
#pragma unroll
                for (int r = 0; r < 4; ++r) alpha_s[rb + r] = al[r];
            }
#pragma unroll
            for (int j = 0; j < 4; ++j) {
                int col = wn * 64 + j * 16 + rl;
#pragma unroll
                for (int r = 0; r < 4; ++r) {
                    float p = __expf(acc[i][j][r] - mn[r]);
                    sm[r] += p;
                    lPK[(rb + r) * 136 + col] = f2bf(p);
                }
            }
#pragma unroll
            for (int jj = 0; jj < 2; ++jj)
#pragma unroll
                for (int r = 0; r < 4; ++r) o[i][jj][r] *= al[r];
#pragma unroll
            for (int r = 0; r < 4; ++r) {
#pragma unroll
                for (int off = 8; off > 0; off >>= 1) sm[r] += __shfl_xor(sm[r], off);
            }
            if (rl == 0) {
#pragma unroll
                for (int r = 0; r < 4; ++r) red_s[wn * 128 + rb + r] = sm[r];
            }
        }
        __syncthreads();                              // barrier 4: sum exchange + P visible
        if (tid < 128) l_s[tid] = l_s[tid] * alpha_s[tid] + red_s[tid] + red_s[128 + tid];

        // PV
#pragma unroll
        for (int ks = 0; ks < 4; ++ks) {
            bf16x8 aP[4], bV[2];
#pragma unroll
            for (int i = 0; i < 4; ++i)
                aP[i] = *(const bf16x8*)&lPK[(wm * 64 + i * 16 + rl) * 136 + ks * 32 + kq * 8];
#pragma unroll
            for (int jj = 0; jj < 2; ++jj) {
                int row = wn * 32 + jj * 16 + rl;
                int sl = (ks * 4 + kq) ^ (row & 15);
                bV[jj] = *(const bf16x8*)&lVt[row * 64 + sl * 4];
            }
#pragma unroll
            for (int i = 0; i < 4; ++i)
#pragma unroll
                for (int jj = 0; jj < 2; ++jj)
                    o[i][jj] = __builtin_amdgcn_mfma_f32_16x16x32_bf16(aP[i], bV[jj], o[i][jj], 0, 0, 0);
        }
    }
    __syncthreads();

    // epilogue: stage O tile (128x64 bf16) in lPK, then coalesced stores
#pragma unroll
    for (int i = 0; i < 4; ++i) {
        int rb = wm * 64 + i * 16 + kq * 4;
        float il[4];
#pragma unroll
        for (int r = 0; r < 4; ++r) il[r] = 1.f / l_s[rb + r];
#pragma unroll
        for (int jj = 0; jj < 2; ++jj) {
            int e = wn * 32 + jj * 16 + rl;
#pragma unroll
            for (int r = 0; r < 4; ++r)
                lPK[(rb + r) * 136 + e] = f2bf(o[i][jj][r] * il[r]);
        }
    }
    __syncthreads();
    u16* Ob = O + hb + (size_t)qg0 * 512;
#pragma unroll
    for (int rep = 0; rep < 4; ++rep) {
        int row = rep * 32 + (tid >> 3);
        int col8 = (tid & 7) * 8;
        *(u16x8*)&Ob[(size_t)row * 512 + col8] = *(const u16x8*)&lPK[row * 136 + col8];
    }
}

// ---------------------------------------------------------------------------
extern "C" void kernel_launch(void* const* d_in, const int* in_sizes, int n_in,
                              void* d_out, int out_size, void* d_ws, size_t ws_size,
                              hipStream_t stream)
{
    const float* x     = (const float*)d_in[0];
    const float* lap   = (const float*)d_in[1];
    const float* emb   = (const float*)d_in[2];
    const float* Wq    = (const float*)d_in[3];
    const float* bq    = (const float*)d_in[4];
    const float* Wk    = (const float*)d_in[5];
    const float* bk    = (const float*)d_in[6];
    const float* Wv    = (const float*)d_in[7];
    const float* bvv   = (const float*)d_in[8];
    const float* g1    = (const float*)d_in[9];
    const float* bb1   = (const float*)d_in[10];
    const float* g2    = (const float*)d_in[11];
    const float* bb2   = (const float*)d_in[12];
    const float* alpha = (const float*)d_in[13];
    const float* beta  = (const float*)d_in[14];
    const float* Wo    = (const float*)d_in[15];
    const float* bo    = (const float*)d_in[16];
    const float* W1    = (const float*)d_in[17];
    const float* b1    = (const float*)d_in[18];
    const float* W2    = (const float*)d_in[19];
    const float* b2    = (const float*)d_in[20];
    float* out = (float*)d_out;

    const size_t SZ = (size_t)4 * 8 * 512 * 512;
    char* w = (char*)d_ws;
    float* bias = (float*)w;  w += (size_t)512 * 512 * 4;   // holds bias^T now
    u16* wqb = (u16*)w; w += (size_t)512 * 512 * 2;
    u16* wkb = (u16*)w; w += (size_t)512 * 512 * 2;
    u16* wvb = (u16*)w; w += (size_t)512 * 512 * 2;
    u16* wob = (u16*)w; w += (size_t)512 * 512 * 2;
    u16* w1b = (u16*)w; w += (size_t)2048 * 512 * 2;
    u16* w2b = (u16*)w; w += (size_t)512 * 2048 * 2;
    u16* xnb = (u16*)w; w += SZ * 2;   // LN1 out; reused as attention output
    u16* qb  = (u16*)w; w += SZ * 2;   // Q; reused as LN2 out
    u16* kb  = (u16*)w; w += SZ * 2;
    u16* vb  = (u16*)w; w += SZ * 2;
    u16* hb  = (u16*)w; w += (size_t)16384 * 2048 * 2;
    float* x1 = out;

    const int M = 16384;
    cvt6_kernel<<<1536, 256, 0, stream>>>(Wq, Wk, Wv, Wo, W1, W2,
                                          wqb, wkb, wvb, wob, w1b, w2b);
    bias_kernel<<<512, 256, 0, stream>>>(emb, lap, alpha, beta, bias);
    ln_kernel<<<M / 4, 256, 0, stream>>>(x, g1, bb1, xnb);
    gemm_qkv<<<dim3(12, 128), 256, 0, stream>>>(xnb, wqb, wkb, wvb, bq, bk, bvv, qb, kb, vb);
    flash_attn<<<dim3(4, 8, 32), 256, 0, stream>>>(qb, kb, vb, bias, xnb);
    gemm128_res<<<dim3(4, 128), 256, 0, stream>>>(xnb, wob, bo, x, x1, M, 512, 512);
    ln_kernel<<<M / 4, 256, 0, stream>>>(x1, g2, bb2, qb);
    gemm_bt<<<dim3(16, 128), 256, 0, stream>>>(qb, w1b, b1, hb, M, 512, 2048, 1);
    gemm128_res<<<dim3(4, 128), 256, 0, stream>>>(hb, w2b, b2, x1, out, M, 2048, 512);
}

// Round 6
// 435.512 us; speedup vs baseline: 1.0112x; 1.0112x over previous
//
#include <hip/hip_runtime.h>

typedef __bf16 bf16x8 __attribute__((ext_vector_type(8)));
typedef unsigned short u16x8 __attribute__((ext_vector_type(8)));
typedef float f32x4 __attribute__((ext_vector_type(4)));
typedef unsigned short u16;

__device__ __forceinline__ float bf2f(u16 u) {
    union { unsigned int i; float f; } x; x.i = ((unsigned int)u) << 16; return x.f;
}
__device__ __forceinline__ u16 f2bf(float f) {
    union { float f; unsigned int i; } x; x.f = f;
    unsigned int u = x.i;
    unsigned int r = (u + 0x7FFFu + ((u >> 16) & 1u)) >> 16;
    return (u16)r;
}

#define GL16(g, l) __builtin_amdgcn_global_load_lds( \
    (__attribute__((address_space(1))) void*)(void*)(g), \
    (__attribute__((address_space(3))) void*)(void*)(l), 16, 0, 0)

// ---------------------------------------------------------------------------
// weights fp32 -> bf16
// ---------------------------------------------------------------------------
__global__ __launch_bounds__(256)
void cvt6_kernel(const float* __restrict__ s0, const float* __restrict__ s1,
                 const float* __restrict__ s2, const float* __restrict__ s3,
                 const float* __restrict__ s4, const float* __restrict__ s5,
                 u16* __restrict__ d0, u16* __restrict__ d1, u16* __restrict__ d2,
                 u16* __restrict__ d3, u16* __restrict__ d4, u16* __restrict__ d5)
{
    int b = blockIdx.x;
    const float* s; u16* d; int base;
    if (b < 512) {
        int t = b >> 7, lb = b & 127;
        s = (t == 0) ? s0 : (t == 1) ? s1 : (t == 2) ? s2 : s3;
        d = (t == 0) ? d0 : (t == 1) ? d1 : (t == 2) ? d2 : d3;
        base = lb * 2048;
    } else if (b < 1024) { s = s4; d = d4; base = (b - 512) * 2048; }
    else                 { s = s5; d = d5; base = (b - 1024) * 2048; }
    int i = base + threadIdx.x * 8;
    float4 a = *(const float4*)&s[i];
    float4 c = *(const float4*)&s[i + 4];
    u16x8 o;
    o[0] = f2bf(a.x); o[1] = f2bf(a.y); o[2] = f2bf(a.z); o[3] = f2bf(a.w);
    o[4] = f2bf(c.x); o[5] = f2bf(c.y); o[6] = f2bf(c.z); o[7] = f2bf(c.w);
    *(u16x8*)&d[i] = o;
}

// ---------------------------------------------------------------------------
// bias^T[j][i] = alpha*softmax_j(relu(E E^T))[i][j] + beta*lap[i][j] + mask
// TRANSPOSED output so flash_attn can float4-load along the q-row axis.
// ---------------------------------------------------------------------------
__global__ __launch_bounds__(256)
void bias_kernel(const float* __restrict__ E, const float* __restrict__ lap,
                 const float* __restrict__ alpha_p, const float* __restrict__ beta_p,
                 float* __restrict__ biasout)
{
    __shared__ float wred[8];
    int tid = threadIdx.x;
    int i = blockIdx.x;
    int lane = tid & 63, wave = tid >> 6;
    int j0 = tid, j1 = tid + 256;
    float s0 = 0.f, s1 = 0.f;
#pragma unroll
    for (int t4 = 0; t4 < 16; ++t4) {
        float4 a  = *(const float4*)&E[i * 64 + t4 * 4];
        float4 e0 = *(const float4*)&E[j0 * 64 + t4 * 4];
        float4 e1 = *(const float4*)&E[j1 * 64 + t4 * 4];
        s0 += a.x * e0.x + a.y * e0.y + a.z * e0.z + a.w * e0.w;
        s1 += a.x * e1.x + a.y * e1.y + a.z * e1.z + a.w * e1.w;
    }
    s0 = fmaxf(s0, 0.f); s1 = fmaxf(s1, 0.f);
    float m = fmaxf(s0, s1);
#pragma unroll
    for (int o = 32; o > 0; o >>= 1) m = fmaxf(m, __shfl_xor(m, o));
    if (lane == 0) wred[wave] = m;
    __syncthreads();
    m = fmaxf(fmaxf(wred[0], wred[1]), fmaxf(wred[2], wred[3]));
    float e0v = __expf(s0 - m), e1v = __expf(s1 - m);
    float sum = e0v + e1v;
#pragma unroll
    for (int o = 32; o > 0; o >>= 1) sum += __shfl_xor(sum, o);
    if (lane == 0) wred[4 + wave] = sum;
    __syncthreads();
    float inv = 1.f / (wred[4] + wred[5] + wred[6] + wred[7]);
    float alpha = alpha_p[0], beta = beta_p[0];
    float lv0 = lap[i * 512 + j0];
    float lv1 = lap[i * 512 + j1];
    // transposed store: biasT[key][query]
    biasout[j0 * 512 + i] = alpha * (e0v * inv) + beta * lv0 + (lv0 != 0.f ? 0.f : -1e9f);
    biasout[j1 * 512 + i] = alpha * (e1v * inv) + beta * lv1 + (lv1 != 0.f ? 0.f : -1e9f);
}

// ---------------------------------------------------------------------------
// LayerNorm D=512, fp32 in, bf16 out
// ---------------------------------------------------------------------------
__global__ __launch_bounds__(256)
void ln_kernel(const float* __restrict__ X, const float* __restrict__ G,
               const float* __restrict__ Bb, u16* __restrict__ Y)
{
    int row = blockIdx.x * 4 + (threadIdx.x >> 6);
    int lane = threadIdx.x & 63;
    const float* xr = X + (size_t)row * 512 + lane * 8;
    float4 a = *(const float4*)xr;
    float4 b = *(const float4*)(xr + 4);
    float v[8] = {a.x, a.y, a.z, a.w, b.x, b.y, b.z, b.w};
    float s = 0.f, ss = 0.f;
#pragma unroll
    for (int i = 0; i < 8; i++) { s += v[i]; ss += v[i] * v[i]; }
#pragma unroll
    for (int o = 32; o > 0; o >>= 1) { s += __shfl_xor(s, o); ss += __shfl_xor(ss, o); }
    float mu = s * (1.f / 512.f);
    float var = ss * (1.f / 512.f) - mu * mu;
    float rstd = rsqrtf(var + 1e-5f);
    float4 g0 = *(const float4*)&G[lane * 8];
    float4 g1 = *(const float4*)&G[lane * 8 + 4];
    float4 b0 = *(const float4*)&Bb[lane * 8];
    float4 b1 = *(const float4*)&Bb[lane * 8 + 4];
    float gv[8] = {g0.x, g0.y, g0.z, g0.w, g1.x, g1.y, g1.z, g1.w};
    float bv[8] = {b0.x, b0.y, b0.z, b0.w, b1.x, b1.y, b1.z, b1.w};
    u16x8 out;
#pragma unroll
    for (int i = 0; i < 8; i++) out[i] = f2bf((v[i] - mu) * rstd * gv[i] + bv[i]);
    *(u16x8*)&Y[(size_t)row * 512 + lane * 8] = out;
}

// ---------------------------------------------------------------------------
// LDS GEMM (m97 pattern), 128x128 tile, XCD-swizzled, bf16 out (mode 0/1).
// Epilogue staged through LDS (stride 136) -> coalesced u16x8 global stores.
// ---------------------------------------------------------------------------
__global__ __launch_bounds__(256)
void gemm_bt(const u16* __restrict__ A, const u16* __restrict__ W,
             const float* __restrict__ bias,
             u16* __restrict__ Cb, int M, int Kd, int Nout, int mode)
{
    __shared__ __align__(16) char smem[128 * 136 * 2];   // 34 KB (>= lA+lB 16 KB)
    u16* lA = (u16*)smem;
    u16* lB = lA + 128 * 32;
    int tid = threadIdx.x;
    int lane = tid & 63, wave = tid >> 6;
    int wm = wave >> 1, wn = wave & 1;
    int bid = blockIdx.y * gridDim.x + blockIdx.x;
    int per = (gridDim.x * gridDim.y) >> 3;
    int lb  = (bid & 7) * per + (bid >> 3);
    int bx = lb % gridDim.x, by = lb / gridDim.x;
    int row0 = by * 128, col0 = bx * 128;
    int rl = lane & 15, kq = lane >> 4;
    f32x4 acc[4][4];
#pragma unroll
    for (int i = 0; i < 4; i++)
#pragma unroll
        for (int j = 0; j < 4; j++) acc[i][j] = (f32x4){0.f, 0.f, 0.f, 0.f};

    int c0 = tid,       sr0 = c0 >> 2, sc0 = (c0 & 3) * 8;
    int c1 = 256 + tid, sr1 = c1 >> 2, sc1 = (c1 & 3) * 8;
    const u16* Abase = A + (size_t)row0 * Kd;
    const u16* Wbase = W + (size_t)col0 * Kd;

    for (int k0 = 0; k0 < Kd; k0 += 32) {
        GL16(Abase + (size_t)sr0 * Kd + k0 + sc0, &lA[c0 * 8]);
        GL16(Abase + (size_t)sr1 * Kd + k0 + sc1, &lA[c1 * 8]);
        GL16(Wbase + (size_t)sr0 * Kd + k0 + sc0, &lB[c0 * 8]);
        GL16(Wbase + (size_t)sr1 * Kd + k0 + sc1, &lB[c1 * 8]);
        __syncthreads();
        bf16x8 af[4], bf[4];
#pragma unroll
        for (int i = 0; i < 4; i++) af[i] = *(const bf16x8*)&lA[(wm * 64 + i * 16 + rl) * 32 + kq * 8];
#pragma unroll
        for (int j = 0; j < 4; j++) bf[j] = *(const bf16x8*)&lB[(wn * 64 + j * 16 + rl) * 32 + kq * 8];
#pragma unroll
        for (int i = 0; i < 4; i++)
#pragma unroll
            for (int j = 0; j < 4; j++)
                acc[i][j] = __builtin_amdgcn_mfma_f32_16x16x32_bf16(af[i], bf[j], acc[i][j], 0, 0, 0);
        __syncthreads();
    }
    // epilogue: stage bf16 tile in LDS, then coalesced stores
    u16* lC = (u16*)smem;
#pragma unroll
    for (int j = 0; j < 4; j++) {
        int col = wn * 64 + j * 16 + rl;
        float bsv = bias[col0 + col];
#pragma unroll
        for (int i = 0; i < 4; i++) {
            int rb = wm * 64 + i * 16 + kq * 4;
#pragma unroll
            for (int r = 0; r < 4; r++) {
                float vo = acc[i][j][r] + bsv;
                if (mode == 1) vo = fmaxf(vo, 0.f);
                lC[(rb + r) * 136 + col] = f2bf(vo);
            }
        }
    }
    __syncthreads();
#pragma unroll
    for (int rep = 0; rep < 8; rep++) {
        int row = rep * 16 + (tid >> 4);
        int col8 = (tid & 15) * 8;
        *(u16x8*)&Cb[(size_t)(row0 + row) * Nout + col0 + col8] = *(const u16x8*)&lC[row * 136 + col8];
    }
}

// ---------------------------------------------------------------------------
// 128x128-tile LDS GEMM, fp32 out with residual, direct-scatter epilogue
// ---------------------------------------------------------------------------
__global__ __launch_bounds__(256)
void gemm128_res(const u16* __restrict__ A, const u16* __restrict__ W,
                 const float* __restrict__ bias, const float* __restrict__ resid,
                 float* __restrict__ Cf, int M, int Kd, int Nout)
{
    __shared__ __align__(16) u16 lA[128 * 32];
    __shared__ __align__(16) u16 lB[128 * 32];
    int tid = threadIdx.x;
    int lane = tid & 63, wave = tid >> 6;
    int wm = wave >> 1, wn = wave & 1;
    int bid = blockIdx.y * gridDim.x + blockIdx.x;
    int per = (gridDim.x * gridDim.y) >> 3;
    int lb  = (bid & 7) * per + (bid >> 3);
    int bx = lb % gridDim.x, by = lb / gridDim.x;
    int row0 = by * 128, col0 = bx * 128;
    int rl = lane & 15, kq = lane >> 4;
    f32x4 acc[4][4];
#pragma unroll
    for (int i = 0; i < 4; i++)
#pragma unroll
        for (int j = 0; j < 4; j++) acc[i][j] = (f32x4){0.f, 0.f, 0.f, 0.f};

    int c0 = tid,       sr0 = c0 >> 2, sc0 = (c0 & 3) * 8;
    int c1 = 256 + tid, sr1 = c1 >> 2, sc1 = (c1 & 3) * 8;
    const u16* Abase = A + (size_t)row0 * Kd;
    const u16* Wbase = W + (size_t)col0 * Kd;

    for (int k0 = 0; k0 < Kd; k0 += 32) {
        GL16(Abase + (size_t)sr0 * Kd + k0 + sc0, &lA[c0 * 8]);
        GL16(Abase + (size_t)sr1 * Kd + k0 + sc1, &lA[c1 * 8]);
        GL16(Wbase + (size_t)sr0 * Kd + k0 + sc0, &lB[c0 * 8]);
        GL16(Wbase + (size_t)sr1 * Kd + k0 + sc1, &lB[c1 * 8]);
        __syncthreads();
        bf16x8 af4[4], bf[4];
#pragma unroll
        for (int i = 0; i < 4; i++) af4[i] = *(const bf16x8*)&lA[(wm * 64 + i * 16 + rl) * 32 + kq * 8];
#pragma unroll
        for (int j = 0; j < 4; j++) bf[j] = *(const bf16x8*)&lB[(wn * 64 + j * 16 + rl) * 32 + kq * 8];
#pragma unroll
        for (int i = 0; i < 4; i++)
#pragma unroll
            for (int j = 0; j < 4; j++)
                acc[i][j] = __builtin_amdgcn_mfma_f32_16x16x32_bf16(af4[i], bf[j], acc[i][j], 0, 0, 0);
        __syncthreads();
    }
    // direct f32 epilogue: per quarter-wave a 64B contiguous run -> coalesced
#pragma unroll
    for (int j = 0; j < 4; j++) {
        int col = col0 + wn * 64 + j * 16 + rl;
        float bsv = bias[col];
#pragma unroll
        for (int i = 0; i < 4; i++) {
            int rb = row0 + wm * 64 + i * 16 + kq * 4;
#pragma unroll
            for (int r = 0; r < 4; r++) {
                size_t idx = (size_t)(rb + r) * Nout + col;
                Cf[idx] = acc[i][j][r] + bsv + resid[idx];
            }
        }
    }
}

// ---------------------------------------------------------------------------
// fused QKV, XCD-swizzled, LDS-staged epilogue
// ---------------------------------------------------------------------------
__global__ __launch_bounds__(256)
void gemm_qkv(const u16* __restrict__ A,
              const u16* __restrict__ W0, const u16* __restrict__ W1, const u16* __restrict__ W2,
              const float* __restrict__ b0, const float* __restrict__ b1, const float* __restrict__ b2,
              u16* __restrict__ C0, u16* __restrict__ C1, u16* __restrict__ C2)
{
    __shared__ __align__(16) char smem[128 * 136 * 2];   // 34 KB
    u16* lA = (u16*)smem;
    u16* lB = lA + 128 * 32;
    const int Kd = 512, Nout = 512;
    int bid = blockIdx.y * gridDim.x + blockIdx.x;
    int per = (gridDim.x * gridDim.y) >> 3;       // 192
    int lb  = (bid & 7) * per + (bid >> 3);
    int rest = lb % 12, by = lb / 12;
    int sel = rest >> 2;
    const u16* W = (sel == 0) ? W0 : (sel == 1) ? W1 : W2;
    const float* bias = (sel == 0) ? b0 : (sel == 1) ? b1 : b2;
    u16* Cb = (sel == 0) ? C0 : (sel == 1) ? C1 : C2;
    int tid = threadIdx.x;
    int lane = tid & 63, wave = tid >> 6;
    int wm = wave >> 1, wn = wave & 1;
    int row0 = by * 128, col0 = (rest & 3) * 128;
    int rl = lane & 15, kq = lane >> 4;
    f32x4 acc[4][4];
#pragma unroll
    for (int i = 0; i < 4; i++)
#pragma unroll
        for (int j = 0; j < 4; j++) acc[i][j] = (f32x4){0.f, 0.f, 0.f, 0.f};
    int c0 = tid,       sr0 = c0 >> 2, sc0 = (c0 & 3) * 8;
    int c1 = 256 + tid, sr1 = c1 >> 2, sc1 = (c1 & 3) * 8;
    const u16* Abase = A + (size_t)row0 * Kd;
    const u16* Wbase = W + (size_t)col0 * Kd;
    for (int k0 = 0; k0 < Kd; k0 += 32) {
        GL16(Abase + (size_t)sr0 * Kd + k0 + sc0, &lA[c0 * 8]);
        GL16(Abase + (size_t)sr1 * Kd + k0 + sc1, &lA[c1 * 8]);
        GL16(Wbase + (size_t)sr0 * Kd + k0 + sc0, &lB[c0 * 8]);
        GL16(Wbase + (size_t)sr1 * Kd + k0 + sc1, &lB[c1 * 8]);
        __syncthreads();
        bf16x8 af[4], bf[4];
#pragma unroll
        for (int i = 0; i < 4; i++) af[i] = *(const bf16x8*)&lA[(wm * 64 + i * 16 + rl) * 32 + kq * 8];
#pragma unroll
        for (int j = 0; j < 4; j++) bf[j] = *(const bf16x8*)&lB[(wn * 64 + j * 16 + rl) * 32 + kq * 8];
#pragma unroll
        for (int i = 0; i < 4; i++)
#pragma unroll
            for (int j = 0; j < 4; j++)
                acc[i][j] = __builtin_amdgcn_mfma_f32_16x16x32_bf16(af[i], bf[j], acc[i][j], 0, 0, 0);
        __syncthreads();
    }
    u16* lC = (u16*)smem;
#pragma unroll
    for (int j = 0; j < 4; j++) {
        int col = wn * 64 + j * 16 + rl;
        float bsv = bias[col0 + col];
#pragma unroll
        for (int i = 0; i < 4; i++) {
            int rb = wm * 64 + i * 16 + kq * 4;
#pragma unroll
            for (int r = 0; r < 4; r++)
                lC[(rb + r) * 136 + col] = f2bf(acc[i][j][r] + bsv);
        }
    }
    __syncthreads();
#pragma unroll
    for (int rep = 0; rep < 8; rep++) {
        int row = rep * 16 + (tid >> 4);
        int col8 = (tid & 15) * 8;
        *(u16x8*)&Cb[(size_t)(row0 + row) * Nout + col0 + col8] = *(const u16x8*)&lC[row * 136 + col8];
    }
}

// ---------------------------------------------------------------------------
// flash attention v5 = baseline register structure (m/alpha in LDS, tid<128
// single-exp update, 5 barriers/t-iter -> 124-VGPR class) + the zero-register
// wins from v2-v4: K/Q XOR swizzle (conflicts 3.67e6 -> 1.18e6), swizzled
// de-padded lVt unioned with lQ (LDS 71680 -> 54272), transposed-bias float4.
// History: m-in-registers cost ~50 VGPRs; paid as spill (121us) or occupancy
// collapse to 1 blk/CU (129us); baseline-structure 124 VGPR ran 80.5us.
// ---------------------------------------------------------------------------
__global__ __launch_bounds__(256)
void flash_attn(const u16* __restrict__ Q, const u16* __restrict__ Km,
                const u16* __restrict__ V, const float* __restrict__ biasT,
                u16* __restrict__ O)
{
    __shared__ __align__(16) char smem[54272];
    u16* lPK      = (u16*)smem;                      // K-stage 128x64 (swz) / P 128x136 / O-stage
    u16* lQ       = (u16*)(smem + 34816);            // Q-stage 128x64 (swz), union with lVt
    unsigned* lVt = (unsigned*)(smem + 34816);       // V^T 64 x 64 dwords, 16B-slot swz
    float* red     = (float*)(smem + 51200);         // 256 f (two wn halves)
    float* m_s     = red + 256;                      // 128 f
    float* mnew_s  = m_s + 128;                      // 128 f
    float* alpha_s = mnew_s + 128;                   // 128 f
    float* l_s     = alpha_s + 128;                  // 128 f  -> total 54272

    int tid = threadIdx.x, lane = tid & 63, wave = tid >> 6;
    int wm = wave >> 1, wn = wave & 1;
    int rl = lane & 15, kq = lane >> 4;
    int qt = blockIdx.x, h = blockIdx.y, bt = blockIdx.z;
    int qg0 = qt * 128;
    size_t hb = (size_t)bt * (512 * 512) + h * 64;
    const u16* Qbase = Q + hb + (size_t)qg0 * 512;
    const u16* Kb0   = Km + hb;
    const u16* Vb0   = V + hb;

    // stage Q: linear LDS dest, inverse-swizzled global source (rule #21)
#pragma unroll
    for (int rep = 0; rep < 4; ++rep) {
        int c = rep * 256 + tid;
        int qr = c >> 3, d0 = (((c & 7) ^ (qr & 7)) * 8);
        GL16(Qbase + (size_t)qr * 512 + d0, &lQ[c * 8]);
    }
    if (tid < 128) { m_s[tid] = -3.0e38f; l_s[tid] = 0.f; }
    __syncthreads();

    bf16x8 af[4][2];
#pragma unroll
    for (int i = 0; i < 4; i++) {
        int row = wm * 64 + i * 16 + rl;
#pragma unroll
        for (int s = 0; s < 2; s++) {
            int sl = (s * 4 + kq) ^ (row & 7);
            af[i][s] = *(const bf16x8*)&lQ[row * 64 + sl * 8];
        }
    }

    f32x4 o[4][2];
#pragma unroll
    for (int i = 0; i < 4; i++)
#pragma unroll
        for (int jj = 0; jj < 2; jj++) o[i][jj] = (f32x4){0.f, 0.f, 0.f, 0.f};

    for (int t = 0; t < 4; ++t) {
        int kv0 = t * 128;
        __syncthreads();                              // barrier 1: buffers reusable
        const u16* Kbase = Kb0 + (size_t)kv0 * 512;
#pragma unroll
        for (int rep = 0; rep < 4; ++rep) {
            int c = rep * 256 + tid;
            int kv = c >> 3, d0 = (((c & 7) ^ (kv & 7)) * 8);
            GL16(Kbase + (size_t)kv * 512 + d0, &lPK[c * 8]);
        }
        const u16* Vbase = Vb0 + (size_t)kv0 * 512;
#pragma unroll
        for (int rep = 0; rep < 2; ++rep) {
            int idx = rep * 256 + tid;
            int p = idx & 63, e0 = (idx >> 6) * 8;
            const u16* vp0 = Vbase + (size_t)(2 * p) * 512 + e0;
            u16x8 v0 = *(const u16x8*)vp0;
            u16x8 v1 = *(const u16x8*)(vp0 + 512);
#pragma unroll
            for (int u = 0; u < 8; ++u) {
                int row = e0 + u;
                int col = ((((p >> 2) ^ (row & 15)) << 2) | (p & 3));
                lVt[row * 64 + col] = (unsigned)v0[u] | ((unsigned)v1[u] << 16);
            }
        }
        __syncthreads();                              // barrier 2: tiles ready

        f32x4 acc[4][4];
#pragma unroll
        for (int j = 0; j < 4; ++j) {
            int row = wn * 64 + j * 16 + rl;
            int sl0 = kq ^ (row & 7), sl1 = (4 + kq) ^ (row & 7);
            bf16x8 bk0 = *(const bf16x8*)&lPK[row * 64 + sl0 * 8];
            bf16x8 bk1 = *(const bf16x8*)&lPK[row * 64 + sl1 * 8];
#pragma unroll
            for (int i = 0; i < 4; ++i) {
                acc[i][j] = __builtin_amdgcn_mfma_f32_16x16x32_bf16(af[i][0], bk0,
                            (f32x4){0.f, 0.f, 0.f, 0.f}, 0, 0, 0);
                acc[i][j] = __builtin_amdgcn_mfma_f32_16x16x32_bf16(af[i][1], bk1, acc[i][j], 0, 0, 0);
            }
        }
        // bias add: transposed table -> one float4 per (i,j)
#pragma unroll
        for (int j = 0; j < 4; ++j) {
            int colg = kv0 + wn * 64 + j * 16 + rl;
            const float* bp = biasT + (size_t)colg * 512 + qg0;
#pragma unroll
            for (int i = 0; i < 4; ++i) {
                float4 bv = *(const float4*)&bp[wm * 64 + i * 16 + kq * 4];
                float bvr[4] = {bv.x, bv.y, bv.z, bv.w};
#pragma unroll
                for (int r = 0; r < 4; ++r)
                    acc[i][j][r] = acc[i][j][r] * 0.125f + bvr[r];
            }
        }
        // row max (this wn half) -> red
#pragma unroll
        for (int i = 0; i < 4; ++i) {
            float mx[4];
#pragma unroll
            for (int r = 0; r < 4; ++r) {
                mx[r] = fmaxf(fmaxf(acc[i][0][r], acc[i][1][r]), fmaxf(acc[i][2][r], acc[i][3][r]));
#pragma unroll
                for (int off = 8; off > 0; off >>= 1) mx[r] = fmaxf(mx[r], __shfl_xor(mx[r], off));
            }
            if (rl == 0) {
                int rb = wm * 64 + i * 16 + kq * 4;
#pragma unroll
                for (int r = 0; r < 4; ++r) red[wn * 128 + rb + r] = mx[r];
            }
        }
        __syncthreads();                              // barrier 3: max exchange
        if (tid < 128) {
            float pm = fmaxf(red[tid], red[128 + tid]);
            float mo = m_s[tid];
            float mn = fmaxf(mo, pm);
            m_s[tid] = mn; mnew_s[tid] = mn;
            alpha_s[tid] = __expf(mo - mn);
        }
        __syncthreads();                              // barrier 4: m/alpha ready

#pragma unroll
        for (int i = 0; i < 4; ++i) {
            int rb = wm * 64 + i * 16 + kq * 4;
            float mn[4], al[4], sm[4];
#pragma unroll
            for (int r = 0; r < 4; ++r) { mn[r] = mnew_s[rb + r]; al[r] = alpha_s[rb + r]; sm[r] = 0.f; }
#pragma unroll
            for (int j = 0; j < 4; ++j) {
                int col = wn * 64 + j * 16 + rl;
#pragma unroll
                for (int r = 0; r < 4; ++r) {
                    float p = __expf(acc[i][j][r] - mn[r]);
                    sm[r] += p;
                    lPK[(rb + r) * 136 + col] = f2bf(p);
                }
            }
#pragma unroll
            for (int jj = 0; jj < 2; ++jj)
#pragma unroll
                for (int r = 0; r < 4; ++r) o[i][jj][r] *= al[r];
#pragma unroll
            for (int r = 0; r < 4; ++r) {
#pragma unroll
                for (int off = 8; off > 0; off >>= 1) sm[r] += __shfl_xor(sm[r], off);
            }
            if (rl == 0) {
#pragma unroll
                for (int r = 0; r < 4; ++r) red[wn * 128 + rb + r] = sm[r];
            }
        }
        __syncthreads();                              // barrier 5: sum exchange + P visible
        if (tid < 128) l_s[tid] = l_s[tid] * alpha_s[tid] + red[tid] + red[128 + tid];

        // PV
#pragma unroll
        for (int ks = 0; ks < 4; ++ks) {
            bf16x8 aP[4], bV[2];
#pragma unroll
            for (int i = 0; i < 4; ++i)
                aP[i] = *(const bf16x8*)&lPK[(wm * 64 + i * 16 + rl) * 136 + ks * 32 + kq * 8];
#pragma unroll
            for (int jj = 0; jj < 2; ++jj) {
                int row = wn * 32 + jj * 16 + rl;
                int sl = (ks * 4 + kq) ^ (row & 15);
                bV[jj] = *(const bf16x8*)&lVt[row * 64 + sl * 4];
            }
#pragma unroll
            for (int i = 0; i < 4; ++i)
#pragma unroll
                for (int jj = 0; jj < 2; ++jj)
                    o[i][jj] = __builtin_amdgcn_mfma_f32_16x16x32_bf16(aP[i], bV[jj], o[i][jj], 0, 0, 0);
        }
    }
    __syncthreads();

    // epilogue: stage O tile (128x64 bf16) in lPK, then coalesced stores
#pragma unroll
    for (int i = 0; i < 4; ++i) {
        int rb = wm * 64 + i * 16 + kq * 4;
        float il[4];
#pragma unroll
        for (int r = 0; r < 4; ++r) il[r] = 1.f / l_s[rb + r];
#pragma unroll
        for (int jj = 0; jj < 2; ++jj) {
            int e = wn * 32 + jj * 16 + rl;
#pragma unroll
            for (int r = 0; r < 4; ++r)
                lPK[(rb + r) * 136 + e] = f2bf(o[i][jj][r] * il[r]);
        }
    }
    __syncthreads();
    u16* Ob = O + hb + (size_t)qg0 * 512;
#pragma unroll
    for (int rep = 0; rep < 4; ++rep) {
        int row = rep * 32 + (tid >> 3);
        int col8 = (tid & 7) * 8;
        *(u16x8*)&Ob[(size_t)row * 512 + col8] = *(const u16x8*)&lPK[row * 136 + col8];
    }
}

// ---------------------------------------------------------------------------
extern "C" void kernel_launch(void* const* d_in, const int* in_sizes, int n_in,
                              void* d_out, int out_size, void* d_ws, size_t ws_size,
                              hipStream_t stream)
{
    const float* x     = (const float*)d_in[0];
    const float* lap   = (const float*)d_in[1];
    const float* emb   = (const float*)d_in[2];
    const float* Wq    = (const float*)d_in[3];
    const float* bq    = (const float*)d_in[4];
    const float* Wk    = (const float*)d_in[5];
    const float* bk    = (const float*)d_in[6];
    const float* Wv    = (const float*)d_in[7];
    const float* bvv   = (const float*)d_in[8];
    const float* g1    = (const float*)d_in[9];
    const float* bb1   = (const float*)d_in[10];
    const float* g2    = (const float*)d_in[11];
    const float* bb2   = (const float*)d_in[12];
    const float* alpha = (const float*)d_in[13];
    const float* beta  = (const float*)d_in[14];
    const float* Wo    = (const float*)d_in[15];
    const float* bo    = (const float*)d_in[16];
    const float* W1    = (const float*)d_in[17];
    const float* b1    = (const float*)d_in[18];
    const float* W2    = (const float*)d_in[19];
    const float* b2    = (const float*)d_in[20];
    float* out = (float*)d_out;

    const size_t SZ = (size_t)4 * 8 * 512 * 512;
    char* w = (char*)d_ws;
    float* bias = (float*)w;  w += (size_t)512 * 512 * 4;   // holds bias^T now
    u16* wqb = (u16*)w; w += (size_t)512 * 512 * 2;
    u16* wkb = (u16*)w; w += (size_t)512 * 512 * 2;
    u16* wvb = (u16*)w; w += (size_t)512 * 512 * 2;
    u16* wob = (u16*)w; w += (size_t)512 * 512 * 2;
    u16* w1b = (u16*)w; w += (size_t)2048 * 512 * 2;
    u16* w2b = (u16*)w; w += (size_t)512 * 2048 * 2;
    u16* xnb = (u16*)w; w += SZ * 2;   // LN1 out; reused as attention output
    u16* qb  = (u16*)w; w += SZ * 2;   // Q; reused as LN2 out
    u16* kb  = (u16*)w; w += SZ * 2;
    u16* vb  = (u16*)w; w += SZ * 2;
    u16* hb  = (u16*)w; w += (size_t)16384 * 2048 * 2;
    float* x1 = out;

    const int M = 16384;
    cvt6_kernel<<<1536, 256, 0, stream>>>(Wq, Wk, Wv, Wo, W1, W2,
                                          wqb, wkb, wvb, wob, w1b, w2b);
    bias_kernel<<<512, 256, 0, stream>>>(emb, lap, alpha, beta, bias);
    ln_kernel<<<M / 4, 256, 0, stream>>>(x, g1, bb1, xnb);
    gemm_qkv<<<dim3(12, 128), 256, 0, stream>>>(xnb, wqb, wkb, wvb, bq, bk, bvv, qb, kb, vb);
    flash_attn<<<dim3(4, 8, 32), 256, 0, stream>>>(qb, kb, vb, bias, xnb);
    gemm128_res<<<dim3(4, 128), 256, 0, stream>>>(xnb, wob, bo, x, x1, M, 512, 512);
    ln_kernel<<<M / 4, 256, 0, stream>>>(x1, g2, bb2, qb);
    gemm_bt<<<dim3(16, 128), 256, 0, stream>>>(qb, w1b, b1, hb, M, 512, 2048, 1);
    gemm128_res<<<dim3(4, 128), 256, 0, stream>>>(hb, w2b, b2, x1, out, M, 2048, 512);
}

// Round 7
// 395.644 us; speedup vs baseline: 1.1131x; 1.1008x over previous
//
#include <hip/hip_runtime.h>

typedef __bf16 bf16x8 __attribute__((ext_vector_type(8)));
typedef unsigned short u16x8 __attribute__((ext_vector_type(8)));
typedef float f32x4 __attribute__((ext_vector_type(4)));
typedef unsigned short u16;

__device__ __forceinline__ float bf2f(u16 u) {
    union { unsigned int i; float f; } x; x.i = ((unsigned int)u) << 16; return x.f;
}
__device__ __forceinline__ u16 f2bf(float f) {
    union { float f; unsigned int i; } x; x.f = f;
    unsigned int u = x.i;
    unsigned int r = (u + 0x7FFFu + ((u >> 16) & 1u)) >> 16;
    return (u16)r;
}

#define GL16(g, l) __builtin_amdgcn_global_load_lds( \
    (__attribute__((address_space(1))) void*)(void*)(g), \
    (__attribute__((address_space(3))) void*)(void*)(l), 16, 0, 0)

// ---------------------------------------------------------------------------
// weights fp32 -> bf16
// ---------------------------------------------------------------------------
__global__ __launch_bounds__(256)
void cvt6_kernel(const float* __restrict__ s0, const float* __restrict__ s1,
                 const float* __restrict__ s2, const float* __restrict__ s3,
                 const float* __restrict__ s4, const float* __restrict__ s5,
                 u16* __restrict__ d0, u16* __restrict__ d1, u16* __restrict__ d2,
                 u16* __restrict__ d3, u16* __restrict__ d4, u16* __restrict__ d5)
{
    int b = blockIdx.x;
    const float* s; u16* d; int base;
    if (b < 512) {
        int t = b >> 7, lb = b & 127;
        s = (t == 0) ? s0 : (t == 1) ? s1 : (t == 2) ? s2 : s3;
        d = (t == 0) ? d0 : (t == 1) ? d1 : (t == 2) ? d2 : d3;
        base = lb * 2048;
    } else if (b < 1024) { s = s4; d = d4; base = (b - 512) * 2048; }
    else                 { s = s5; d = d5; base = (b - 1024) * 2048; }
    int i = base + threadIdx.x * 8;
    float4 a = *(const float4*)&s[i];
    float4 c = *(const float4*)&s[i + 4];
    u16x8 o;
    o[0] = f2bf(a.x); o[1] = f2bf(a.y); o[2] = f2bf(a.z); o[3] = f2bf(a.w);
    o[4] = f2bf(c.x); o[5] = f2bf(c.y); o[6] = f2bf(c.z); o[7] = f2bf(c.w);
    *(u16x8*)&d[i] = o;
}

// ---------------------------------------------------------------------------
// bias^T[j][i] = alpha*softmax_j(relu(E E^T))[i][j] + beta*lap[i][j] + mask
// TRANSPOSED output so flash_attn can float4-load along the q-row axis.
// ---------------------------------------------------------------------------
__global__ __launch_bounds__(256)
void bias_kernel(const float* __restrict__ E, const float* __restrict__ lap,
                 const float* __restrict__ alpha_p, const float* __restrict__ beta_p,
                 float* __restrict__ biasout)
{
    __shared__ float wred[8];
    int tid = threadIdx.x;
    int i = blockIdx.x;
    int lane = tid & 63, wave = tid >> 6;
    int j0 = tid, j1 = tid + 256;
    float s0 = 0.f, s1 = 0.f;
#pragma unroll
    for (int t4 = 0; t4 < 16; ++t4) {
        float4 a  = *(const float4*)&E[i * 64 + t4 * 4];
        float4 e0 = *(const float4*)&E[j0 * 64 + t4 * 4];
        float4 e1 = *(const float4*)&E[j1 * 64 + t4 * 4];
        s0 += a.x * e0.x + a.y * e0.y + a.z * e0.z + a.w * e0.w;
        s1 += a.x * e1.x + a.y * e1.y + a.z * e1.z + a.w * e1.w;
    }
    s0 = fmaxf(s0, 0.f); s1 = fmaxf(s1, 0.f);
    float m = fmaxf(s0, s1);
#pragma unroll
    for (int o = 32; o > 0; o >>= 1) m = fmaxf(m, __shfl_xor(m, o));
    if (lane == 0) wred[wave] = m;
    __syncthreads();
    m = fmaxf(fmaxf(wred[0], wred[1]), fmaxf(wred[2], wred[3]));
    float e0v = __expf(s0 - m), e1v = __expf(s1 - m);
    float sum = e0v + e1v;
#pragma unroll
    for (int o = 32; o > 0; o >>= 1) sum += __shfl_xor(sum, o);
    if (lane == 0) wred[4 + wave] = sum;
    __syncthreads();
    float inv = 1.f / (wred[4] + wred[5] + wred[6] + wred[7]);
    float alpha = alpha_p[0], beta = beta_p[0];
    float lv0 = lap[i * 512 + j0];
    float lv1 = lap[i * 512 + j1];
    // transposed store: biasT[key][query]
    biasout[j0 * 512 + i] = alpha * (e0v * inv) + beta * lv0 + (lv0 != 0.f ? 0.f : -1e9f);
    biasout[j1 * 512 + i] = alpha * (e1v * inv) + beta * lv1 + (lv1 != 0.f ? 0.f : -1e9f);
}

// ---------------------------------------------------------------------------
// LayerNorm D=512, fp32 in, bf16 out
// ---------------------------------------------------------------------------
__global__ __launch_bounds__(256)
void ln_kernel(const float* __restrict__ X, const float* __restrict__ G,
               const float* __restrict__ Bb, u16* __restrict__ Y)
{
    int row = blockIdx.x * 4 + (threadIdx.x >> 6);
    int lane = threadIdx.x & 63;
    const float* xr = X + (size_t)row * 512 + lane * 8;
    float4 a = *(const float4*)xr;
    float4 b = *(const float4*)(xr + 4);
    float v[8] = {a.x, a.y, a.z, a.w, b.x, b.y, b.z, b.w};
    float s = 0.f, ss = 0.f;
#pragma unroll
    for (int i = 0; i < 8; i++) { s += v[i]; ss += v[i] * v[i]; }
#pragma unroll
    for (int o = 32; o > 0; o >>= 1) { s += __shfl_xor(s, o); ss += __shfl_xor(ss, o); }
    float mu = s * (1.f / 512.f);
    float var = ss * (1.f / 512.f) - mu * mu;
    float rstd = rsqrtf(var + 1e-5f);
    float4 g0 = *(const float4*)&G[lane * 8];
    float4 g1 = *(const float4*)&G[lane * 8 + 4];
    float4 b0 = *(const float4*)&Bb[lane * 8];
    float4 b1 = *(const float4*)&Bb[lane * 8 + 4];
    float gv[8] = {g0.x, g0.y, g0.z, g0.w, g1.x, g1.y, g1.z, g1.w};
    float bv[8] = {b0.x, b0.y, b0.z, b0.w, b1.x, b1.y, b1.z, b1.w};
    u16x8 out;
#pragma unroll
    for (int i = 0; i < 8; i++) out[i] = f2bf((v[i] - mu) * rstd * gv[i] + bv[i]);
    *(u16x8*)&Y[(size_t)row * 512 + lane * 8] = out;
}

// ---------------------------------------------------------------------------
// LDS GEMM (m97 pattern), 128x128 tile, XCD-swizzled, bf16 out (mode 0/1).
// Epilogue staged through LDS (stride 136) -> coalesced u16x8 global stores.
// ---------------------------------------------------------------------------
__global__ __launch_bounds__(256)
void gemm_bt(const u16* __restrict__ A, const u16* __restrict__ W,
             const float* __restrict__ bias,
             u16* __restrict__ Cb, int M, int Kd, int Nout, int mode)
{
    __shared__ __align__(16) char smem[128 * 136 * 2];   // 34 KB (>= lA+lB 16 KB)
    u16* lA = (u16*)smem;
    u16* lB = lA + 128 * 32;
    int tid = threadIdx.x;
    int lane = tid & 63, wave = tid >> 6;
    int wm = wave >> 1, wn = wave & 1;
    int bid = blockIdx.y * gridDim.x + blockIdx.x;
    int per = (gridDim.x * gridDim.y) >> 3;
    int lb  = (bid & 7) * per + (bid >> 3);
    int bx = lb % gridDim.x, by = lb / gridDim.x;
    int row0 = by * 128, col0 = bx * 128;
    int rl = lane & 15, kq = lane >> 4;
    f32x4 acc[4][4];
#pragma unroll
    for (int i = 0; i < 4; i++)
#pragma unroll
        for (int j = 0; j < 4; j++) acc[i][j] = (f32x4){0.f, 0.f, 0.f, 0.f};

    int c0 = tid,       sr0 = c0 >> 2, sc0 = (c0 & 3) * 8;
    int c1 = 256 + tid, sr1 = c1 >> 2, sc1 = (c1 & 3) * 8;
    const u16* Abase = A + (size_t)row0 * Kd;
    const u16* Wbase = W + (size_t)col0 * Kd;

    for (int k0 = 0; k0 < Kd; k0 += 32) {
        GL16(Abase + (size_t)sr0 * Kd + k0 + sc0, &lA[c0 * 8]);
        GL16(Abase + (size_t)sr1 * Kd + k0 + sc1, &lA[c1 * 8]);
        GL16(Wbase + (size_t)sr0 * Kd + k0 + sc0, &lB[c0 * 8]);
        GL16(Wbase + (size_t)sr1 * Kd + k0 + sc1, &lB[c1 * 8]);
        __syncthreads();
        bf16x8 af[4], bf[4];
#pragma unroll
        for (int i = 0; i < 4; i++) af[i] = *(const bf16x8*)&lA[(wm * 64 + i * 16 + rl) * 32 + kq * 8];
#pragma unroll
        for (int j = 0; j < 4; j++) bf[j] = *(const bf16x8*)&lB[(wn * 64 + j * 16 + rl) * 32 + kq * 8];
#pragma unroll
        for (int i = 0; i < 4; i++)
#pragma unroll
            for (int j = 0; j < 4; j++)
                acc[i][j] = __builtin_amdgcn_mfma_f32_16x16x32_bf16(af[i], bf[j], acc[i][j], 0, 0, 0);
        __syncthreads();
    }
    // epilogue: stage bf16 tile in LDS, then coalesced stores
    u16* lC = (u16*)smem;
#pragma unroll
    for (int j = 0; j < 4; j++) {
        int col = wn * 64 + j * 16 + rl;
        float bsv = bias[col0 + col];
#pragma unroll
        for (int i = 0; i < 4; i++) {
            int rb = wm * 64 + i * 16 + kq * 4;
#pragma unroll
            for (int r = 0; r < 4; r++) {
                float vo = acc[i][j][r] + bsv;
                if (mode == 1) vo = fmaxf(vo, 0.f);
                lC[(rb + r) * 136 + col] = f2bf(vo);
            }
        }
    }
    __syncthreads();
#pragma unroll
    for (int rep = 0; rep < 8; rep++) {
        int row = rep * 16 + (tid >> 4);
        int col8 = (tid & 15) * 8;
        *(u16x8*)&Cb[(size_t)(row0 + row) * Nout + col0 + col8] = *(const u16x8*)&lC[row * 136 + col8];
    }
}

// ---------------------------------------------------------------------------
// 128x128-tile LDS GEMM, fp32 out with residual, direct-scatter epilogue
// ---------------------------------------------------------------------------
__global__ __launch_bounds__(256)
void gemm128_res(const u16* __restrict__ A, const u16* __restrict__ W,
                 const float* __restrict__ bias, const float* __restrict__ resid,
                 float* __restrict__ Cf, int M, int Kd, int Nout)
{
    __shared__ __align__(16) u16 lA[128 * 32];
    __shared__ __align__(16) u16 lB[128 * 32];
    int tid = threadIdx.x;
    int lane = tid & 63, wave = tid >> 6;
    int wm = wave >> 1, wn = wave & 1;
    int bid = blockIdx.y * gridDim.x + blockIdx.x;
    int per = (gridDim.x * gridDim.y) >> 3;
    int lb  = (bid & 7) * per + (bid >> 3);
    int bx = lb % gridDim.x, by = lb / gridDim.x;
    int row0 = by * 128, col0 = bx * 128;
    int rl = lane & 15, kq = lane >> 4;
    f32x4 acc[4][4];
#pragma unroll
    for (int i = 0; i < 4; i++)
#pragma unroll
        for (int j = 0; j < 4; j++) acc[i][j] = (f32x4){0.f, 0.f, 0.f, 0.f};

    int c0 = tid,       sr0 = c0 >> 2, sc0 = (c0 & 3) * 8;
    int c1 = 256 + tid, sr1 = c1 >> 2, sc1 = (c1 & 3) * 8;
    const u16* Abase = A + (size_t)row0 * Kd;
    const u16* Wbase = W + (size_t)col0 * Kd;

    for (int k0 = 0; k0 < Kd; k0 += 32) {
        GL16(Abase + (size_t)sr0 * Kd + k0 + sc0, &lA[c0 * 8]);
        GL16(Abase + (size_t)sr1 * Kd + k0 + sc1, &lA[c1 * 8]);
        GL16(Wbase + (size_t)sr0 * Kd + k0 + sc0, &lB[c0 * 8]);
        GL16(Wbase + (size_t)sr1 * Kd + k0 + sc1, &lB[c1 * 8]);
        __syncthreads();
        bf16x8 af4[4], bf[4];
#pragma unroll
        for (int i = 0; i < 4; i++) af4[i] = *(const bf16x8*)&lA[(wm * 64 + i * 16 + rl) * 32 + kq * 8];
#pragma unroll
        for (int j = 0; j < 4; j++) bf[j] = *(const bf16x8*)&lB[(wn * 64 + j * 16 + rl) * 32 + kq * 8];
#pragma unroll
        for (int i = 0; i < 4; i++)
#pragma unroll
            for (int j = 0; j < 4; j++)
                acc[i][j] = __builtin_amdgcn_mfma_f32_16x16x32_bf16(af4[i], bf[j], acc[i][j], 0, 0, 0);
        __syncthreads();
    }
    // direct f32 epilogue: per quarter-wave a 64B contiguous run -> coalesced
#pragma unroll
    for (int j = 0; j < 4; j++) {
        int col = col0 + wn * 64 + j * 16 + rl;
        float bsv = bias[col];
#pragma unroll
        for (int i = 0; i < 4; i++) {
            int rb = row0 + wm * 64 + i * 16 + kq * 4;
#pragma unroll
            for (int r = 0; r < 4; r++) {
                size_t idx = (size_t)(rb + r) * Nout + col;
                Cf[idx] = acc[i][j][r] + bsv + resid[idx];
            }
        }
    }
}

// ---------------------------------------------------------------------------
// fused QKV, XCD-swizzled, LDS-staged epilogue
// ---------------------------------------------------------------------------
__global__ __launch_bounds__(256)
void gemm_qkv(const u16* __restrict__ A,
              const u16* __restrict__ W0, const u16* __restrict__ W1, const u16* __restrict__ W2,
              const float* __restrict__ b0, const float* __restrict__ b1, const float* __restrict__ b2,
              u16* __restrict__ C0, u16* __restrict__ C1, u16* __restrict__ C2)
{
    __shared__ __align__(16) char smem[128 * 136 * 2];   // 34 KB
    u16* lA = (u16*)smem;
    u16* lB = lA + 128 * 32;
    const int Kd = 512, Nout = 512;
    int bid = blockIdx.y * gridDim.x + blockIdx.x;
    int per = (gridDim.x * gridDim.y) >> 3;       // 192
    int lb  = (bid & 7) * per + (bid >> 3);
    int rest = lb % 12, by = lb / 12;
    int sel = rest >> 2;
    const u16* W = (sel == 0) ? W0 : (sel == 1) ? W1 : W2;
    const float* bias = (sel == 0) ? b0 : (sel == 1) ? b1 : b2;
    u16* Cb = (sel == 0) ? C0 : (sel == 1) ? C1 : C2;
    int tid = threadIdx.x;
    int lane = tid & 63, wave = tid >> 6;
    int wm = wave >> 1, wn = wave & 1;
    int row0 = by * 128, col0 = (rest & 3) * 128;
    int rl = lane & 15, kq = lane >> 4;
    f32x4 acc[4][4];
#pragma unroll
    for (int i = 0; i < 4; i++)
#pragma unroll
        for (int j = 0; j < 4; j++) acc[i][j] = (f32x4){0.f, 0.f, 0.f, 0.f};
    int c0 = tid,       sr0 = c0 >> 2, sc0 = (c0 & 3) * 8;
    int c1 = 256 + tid, sr1 = c1 >> 2, sc1 = (c1 & 3) * 8;
    const u16* Abase = A + (size_t)row0 * Kd;
    const u16* Wbase = W + (size_t)col0 * Kd;
    for (int k0 = 0; k0 < Kd; k0 += 32) {
        GL16(Abase + (size_t)sr0 * Kd + k0 + sc0, &lA[c0 * 8]);
        GL16(Abase + (size_t)sr1 * Kd + k0 + sc1, &lA[c1 * 8]);
        GL16(Wbase + (size_t)sr0 * Kd + k0 + sc0, &lB[c0 * 8]);
        GL16(Wbase + (size_t)sr1 * Kd + k0 + sc1, &lB[c1 * 8]);
        __syncthreads();
        bf16x8 af[4], bf[4];
#pragma unroll
        for (int i = 0; i < 4; i++) af[i] = *(const bf16x8*)&lA[(wm * 64 + i * 16 + rl) * 32 + kq * 8];
#pragma unroll
        for (int j = 0; j < 4; j++) bf[j] = *(const bf16x8*)&lB[(wn * 64 + j * 16 + rl) * 32 + kq * 8];
#pragma unroll
        for (int i = 0; i < 4; i++)
#pragma unroll
            for (int j = 0; j < 4; j++)
                acc[i][j] = __builtin_amdgcn_mfma_f32_16x16x32_bf16(af[i], bf[j], acc[i][j], 0, 0, 0);
        __syncthreads();
    }
    u16* lC = (u16*)smem;
#pragma unroll
    for (int j = 0; j < 4; j++) {
        int col = wn * 64 + j * 16 + rl;
        float bsv = bias[col0 + col];
#pragma unroll
        for (int i = 0; i < 4; i++) {
            int rb = wm * 64 + i * 16 + kq * 4;
#pragma unroll
            for (int r = 0; r < 4; r++)
                lC[(rb + r) * 136 + col] = f2bf(acc[i][j][r] + bsv);
        }
    }
    __syncthreads();
#pragma unroll
    for (int rep = 0; rep < 8; rep++) {
        int row = rep * 16 + (tid >> 4);
        int col8 = (tid & 15) * 8;
        *(u16x8*)&Cb[(size_t)(row0 + row) * Nout + col0 + col8] = *(const u16x8*)&lC[row * 136 + col8];
    }
}

// ---------------------------------------------------------------------------
// flash attention v6 = v5 + __launch_bounds__(256,2).
// Unified-file model (fits all rounds): VGPR_Count excludes ~96 AGPRs
// (acc 64 + o 32). 2-waves/SIMD needs arch+acc <= 256 -> arch <= ~160.
// r0: 124+96=220 -> 2 blk, 80.5us. r5: 164+96=260 -> 1 blk, 126us.
// (256,2) re-imposes the cap; v5's LDS-m structure is the 124-VGPR class
// (baseline proof), so no spill expected (tripwire: WRITE_SIZE >> 16384KB).
// ---------------------------------------------------------------------------
__global__ __launch_bounds__(256, 2)
void flash_attn(const u16* __restrict__ Q, const u16* __restrict__ Km,
                const u16* __restrict__ V, const float* __restrict__ biasT,
                u16* __restrict__ O)
{
    __shared__ __align__(16) char smem[54272];
    u16* lPK      = (u16*)smem;                      // K-stage 128x64 (swz) / P 128x136 / O-stage
    u16* lQ       = (u16*)(smem + 34816);            // Q-stage 128x64 (swz), union with lVt
    unsigned* lVt = (unsigned*)(smem + 34816);       // V^T 64 x 64 dwords, 16B-slot swz
    float* red     = (float*)(smem + 51200);         // 256 f (two wn halves)
    float* m_s     = red + 256;                      // 128 f
    float* mnew_s  = m_s + 128;                      // 128 f
    float* alpha_s = mnew_s + 128;                   // 128 f
    float* l_s     = alpha_s + 128;                  // 128 f  -> total 54272

    int tid = threadIdx.x, lane = tid & 63, wave = tid >> 6;
    int wm = wave >> 1, wn = wave & 1;
    int rl = lane & 15, kq = lane >> 4;
    int qt = blockIdx.x, h = blockIdx.y, bt = blockIdx.z;
    int qg0 = qt * 128;
    size_t hb = (size_t)bt * (512 * 512) + h * 64;
    const u16* Qbase = Q + hb + (size_t)qg0 * 512;
    const u16* Kb0   = Km + hb;
    const u16* Vb0   = V + hb;

    // stage Q: linear LDS dest, inverse-swizzled global source (rule #21)
#pragma unroll
    for (int rep = 0; rep < 4; ++rep) {
        int c = rep * 256 + tid;
        int qr = c >> 3, d0 = (((c & 7) ^ (qr & 7)) * 8);
        GL16(Qbase + (size_t)qr * 512 + d0, &lQ[c * 8]);
    }
    if (tid < 128) { m_s[tid] = -3.0e38f; l_s[tid] = 0.f; }
    __syncthreads();

    bf16x8 af[4][2];
#pragma unroll
    for (int i = 0; i < 4; i++) {
        int row = wm * 64 + i * 16 + rl;
#pragma unroll
        for (int s = 0; s < 2; s++) {
            int sl = (s * 4 + kq) ^ (row & 7);
            af[i][s] = *(const bf16x8*)&lQ[row * 64 + sl * 8];
        }
    }

    f32x4 o[4][2];
#pragma unroll
    for (int i = 0; i < 4; i++)
#pragma unroll
        for (int jj = 0; jj < 2; jj++) o[i][jj] = (f32x4){0.f, 0.f, 0.f, 0.f};

    for (int t = 0; t < 4; ++t) {
        int kv0 = t * 128;
        __syncthreads();                              // barrier 1: buffers reusable
        const u16* Kbase = Kb0 + (size_t)kv0 * 512;
#pragma unroll
        for (int rep = 0; rep < 4; ++rep) {
            int c = rep * 256 + tid;
            int kv = c >> 3, d0 = (((c & 7) ^ (kv & 7)) * 8);
            GL16(Kbase + (size_t)kv * 512 + d0, &lPK[c * 8]);
        }
        const u16* Vbase = Vb0 + (size_t)kv0 * 512;
#pragma unroll
        for (int rep = 0; rep < 2; ++rep) {
            int idx = rep * 256 + tid;
            int p = idx & 63, e0 = (idx >> 6) * 8;
            const u16* vp0 = Vbase + (size_t)(2 * p) * 512 + e0;
            u16x8 v0 = *(const u16x8*)vp0;
            u16x8 v1 = *(const u16x8*)(vp0 + 512);
#pragma unroll
            for (int u = 0; u < 8; ++u) {
                int row = e0 + u;
                int col = ((((p >> 2) ^ (row & 15)) << 2) | (p & 3));
                lVt[row * 64 + col] = (unsigned)v0[u] | ((unsigned)v1[u] << 16);
            }
        }
        __syncthreads();                              // barrier 2: tiles ready

        f32x4 acc[4][4];
#pragma unroll
        for (int j = 0; j < 4; ++j) {
            int row = wn * 64 + j * 16 + rl;
            int sl0 = kq ^ (row & 7), sl1 = (4 + kq) ^ (row & 7);
            bf16x8 bk0 = *(const bf16x8*)&lPK[row * 64 + sl0 * 8];
            bf16x8 bk1 = *(const bf16x8*)&lPK[row * 64 + sl1 * 8];
#pragma unroll
            for (int i = 0; i < 4; ++i) {
                acc[i][j] = __builtin_amdgcn_mfma_f32_16x16x32_bf16(af[i][0], bk0,
                            (f32x4){0.f, 0.f, 0.f, 0.f}, 0, 0, 0);
                acc[i][j] = __builtin_amdgcn_mfma_f32_16x16x32_bf16(af[i][1], bk1, acc[i][j], 0, 0, 0);
            }
        }
        // bias add: transposed table -> one float4 per (i,j)
#pragma unroll
        for (int j = 0; j < 4; ++j) {
            int colg = kv0 + wn * 64 + j * 16 + rl;
            const float* bp = biasT + (size_t)colg * 512 + qg0;
#pragma unroll
            for (int i = 0; i < 4; ++i) {
                float4 bv = *(const float4*)&bp[wm * 64 + i * 16 + kq * 4];
                float bvr[4] = {bv.x, bv.y, bv.z, bv.w};
#pragma unroll
                for (int r = 0; r < 4; ++r)
                    acc[i][j][r] = acc[i][j][r] * 0.125f + bvr[r];
            }
        }
        // row max (this wn half) -> red
#pragma unroll
        for (int i = 0; i < 4; ++i) {
            float mx[4];
#pragma unroll
            for (int r = 0; r < 4; ++r) {
                mx[r] = fmaxf(fmaxf(acc[i][0][r], acc[i][1][r]), fmaxf(acc[i][2][r], acc[i][3][r]));
#pragma unroll
                for (int off = 8; off > 0; off >>= 1) mx[r] = fmaxf(mx[r], __shfl_xor(mx[r], off));
            }
            if (rl == 0) {
                int rb = wm * 64 + i * 16 + kq * 4;
#pragma unroll
                for (int r = 0; r < 4; ++r) red[wn * 128 + rb + r] = mx[r];
            }
        }
        __syncthreads();                              // barrier 3: max exchange
        if (tid < 128) {
            float pm = fmaxf(red[tid], red[128 + tid]);
            float mo = m_s[tid];
            float mn = fmaxf(mo, pm);
            m_s[tid] = mn; mnew_s[tid] = mn;
            alpha_s[tid] = __expf(mo - mn);
        }
        __syncthreads();                              // barrier 4: m/alpha ready

#pragma unroll
        for (int i = 0; i < 4; ++i) {
            int rb = wm * 64 + i * 16 + kq * 4;
            float mn[4], al[4], sm[4];
#pragma unroll
            for (int r = 0; r < 4; ++r) { mn[r] = mnew_s[rb + r]; al[r] = alpha_s[rb + r]; sm[r] = 0.f; }
#pragma unroll
            for (int j = 0; j < 4; ++j) {
                int col = wn * 64 + j * 16 + rl;
#pragma unroll
                for (int r = 0; r < 4; ++r) {
                    float p = __expf(acc[i][j][r] - mn[r]);
                    sm[r] += p;
                    lPK[(rb + r) * 136 + col] = f2bf(p);
                }
            }
#pragma unroll
            for (int jj = 0; jj < 2; ++jj)
#pragma unroll
                for (int r = 0; r < 4; ++r) o[i][jj][r] *= al[r];
#pragma unroll
            for (int r = 0; r < 4; ++r) {
#pragma unroll
                for (int off = 8; off > 0; off >>= 1) sm[r] += __shfl_xor(sm[r], off);
            }
            if (rl == 0) {
#pragma unroll
                for (int r = 0; r < 4; ++r) red[wn * 128 + rb + r] = sm[r];
            }
        }
        __syncthreads();                              // barrier 5: sum exchange + P visible
        if (tid < 128) l_s[tid] = l_s[tid] * alpha_s[tid] + red[tid] + red[128 + tid];

        // PV
#pragma unroll
        for (int ks = 0; ks < 4; ++ks) {
            bf16x8 aP[4], bV[2];
#pragma unroll
            for (int i = 0; i < 4; ++i)
                aP[i] = *(const bf16x8*)&lPK[(wm * 64 + i * 16 + rl) * 136 + ks * 32 + kq * 8];
#pragma unroll
            for (int jj = 0; jj < 2; ++jj) {
                int row = wn * 32 + jj * 16 + rl;
                int sl = (ks * 4 + kq) ^ (row & 15);
                bV[jj] = *(const bf16x8*)&lVt[row * 64 + sl * 4];
            }
#pragma unroll
            for (int i = 0; i < 4; ++i)
#pragma unroll
                for (int jj = 0; jj < 2; ++jj)
                    o[i][jj] = __builtin_amdgcn_mfma_f32_16x16x32_bf16(aP[i], bV[jj], o[i][jj], 0, 0, 0);
        }
    }
    __syncthreads();

    // epilogue: stage O tile (128x64 bf16) in lPK, then coalesced stores
#pragma unroll
    for (int i = 0; i < 4; ++i) {
        int rb = wm * 64 + i * 16 + kq * 4;
        float il[4];
#pragma unroll
        for (int r = 0; r < 4; ++r) il[r] = 1.f / l_s[rb + r];
#pragma unroll
        for (int jj = 0; jj < 2; ++jj) {
            int e = wn * 32 + jj * 16 + rl;
#pragma unroll
            for (int r = 0; r < 4; ++r)
                lPK[(rb + r) * 136 + e] = f2bf(o[i][jj][r] * il[r]);
        }
    }
    __syncthreads();
    u16* Ob = O + hb + (size_t)qg0 * 512;
#pragma unroll
    for (int rep = 0; rep < 4; ++rep) {
        int row = rep * 32 + (tid >> 3);
        int col8 = (tid & 7) * 8;
        *(u16x8*)&Ob[(size_t)row * 512 + col8] = *(const u16x8*)&lPK[row * 136 + col8];
    }
}

// ---------------------------------------------------------------------------
extern "C" void kernel_launch(void* const* d_in, const int* in_sizes, int n_in,
                              void* d_out, int out_size, void* d_ws, size_t ws_size,
                              hipStream_t stream)
{
    const float* x     = (const float*)d_in[0];
    const float* lap   = (const float*)d_in[1];
    const float* emb   = (const float*)d_in[2];
    const float* Wq    = (const float*)d_in[3];
    const float* bq    = (const float*)d_in[4];
    const float* Wk    = (const float*)d_in[5];
    const float* bk    = (const float*)d_in[6];
    const float* Wv    = (const float*)d_in[7];
    const float* bvv   = (const float*)d_in[8];
    const float* g1    = (const float*)d_in[9];
    const float* bb1   = (const float*)d_in[10];
    const float* g2    = (const float*)d_in[11];
    const float* bb2   = (const float*)d_in[12];
    const float* alpha = (const float*)d_in[13];
    const float* beta  = (const float*)d_in[14];
    const float* Wo    = (const float*)d_in[15];
    const float* bo    = (const float*)d_in[16];
    const float* W1    = (const float*)d_in[17];
    const float* b1    = (const float*)d_in[18];
    const float* W2    = (const float*)d_in[19];
    const float* b2    = (const float*)d_in[20];
    float* out = (float*)d_out;

    const size_t SZ = (size_t)4 * 8 * 512 * 512;
    char* w = (char*)d_ws;
    float* bias = (float*)w;  w += (size_t)512 * 512 * 4;   // holds bias^T now
    u16* wqb = (u16*)w; w += (size_t)512 * 512 * 2;
    u16* wkb = (u16*)w; w += (size_t)512 * 512 * 2;
    u16* wvb = (u16*)w; w += (size_t)512 * 512 * 2;
    u16* wob = (u16*)w; w += (size_t)512 * 512 * 2;
    u16* w1b = (u16*)w; w += (size_t)2048 * 512 * 2;
    u16* w2b = (u16*)w; w += (size_t)512 * 2048 * 2;
    u16* xnb = (u16*)w; w += SZ * 2;   // LN1 out; reused as attention output
    u16* qb  = (u16*)w; w += SZ * 2;   // Q; reused as LN2 out
    u16* kb  = (u16*)w; w += SZ * 2;
    u16* vb  = (u16*)w; w += SZ * 2;
    u16* hb  = (u16*)w; w += (size_t)16384 * 2048 * 2;
    float* x1 = out;

    const int M = 16384;
    cvt6_kernel<<<1536, 256, 0, stream>>>(Wq, Wk, Wv, Wo, W1, W2,
                                          wqb, wkb, wvb, wob, w1b, w2b);
    bias_kernel<<<512, 256, 0, stream>>>(emb, lap, alpha, beta, bias);
    ln_kernel<<<M / 4, 256, 0, stream>>>(x, g1, bb1, xnb);
    gemm_qkv<<<dim3(12, 128), 256, 0, stream>>>(xnb, wqb, wkb, wvb, bq, bk, bvv, qb, kb, vb);
    flash_attn<<<dim3(4, 8, 32), 256, 0, stream>>>(qb, kb, vb, bias, xnb);
    gemm128_res<<<dim3(4, 128), 256, 0, stream>>>(xnb, wob, bo, x, x1, M, 512, 512);
    ln_kernel<<<M / 4, 256, 0, stream>>>(x1, g2, bb2, qb);
    gemm_bt<<<dim3(16, 128), 256, 0, stream>>>(qb, w1b, b1, hb, M, 512, 2048, 1);
    gemm128_res<<<dim3(4, 128), 256, 0, stream>>>(hb, w2b, b2, x1, out, M, 2048, 512);
}

// Round 8
// 393.472 us; speedup vs baseline: 1.1192x; 1.0055x over previous
//
#include <hip/hip_runtime.h>

typedef __bf16 bf16x8 __attribute__((ext_vector_type(8)));
typedef unsigned short u16x8 __attribute__((ext_vector_type(8)));
typedef float f32x4 __attribute__((ext_vector_type(4)));
typedef unsigned short u16;

__device__ __forceinline__ float bf2f(u16 u) {
    union { unsigned int i; float f; } x; x.i = ((unsigned int)u) << 16; return x.f;
}
__device__ __forceinline__ u16 f2bf(float f) {
    union { float f; unsigned int i; } x; x.f = f;
    unsigned int u = x.i;
    unsigned int r = (u + 0x7FFFu + ((u >> 16) & 1u)) >> 16;
    return (u16)r;
}

#define GL16(g, l) __builtin_amdgcn_global_load_lds( \
    (__attribute__((address_space(1))) void*)(void*)(g), \
    (__attribute__((address_space(3))) void*)(void*)(l), 16, 0, 0)

// ---------------------------------------------------------------------------
// weights fp32 -> bf16
// ---------------------------------------------------------------------------
__global__ __launch_bounds__(256)
void cvt6_kernel(const float* __restrict__ s0, const float* __restrict__ s1,
                 const float* __restrict__ s2, const float* __restrict__ s3,
                 const float* __restrict__ s4, const float* __restrict__ s5,
                 u16* __restrict__ d0, u16* __restrict__ d1, u16* __restrict__ d2,
                 u16* __restrict__ d3, u16* __restrict__ d4, u16* __restrict__ d5)
{
    int b = blockIdx.x;
    const float* s; u16* d; int base;
    if (b < 512) {
        int t = b >> 7, lb = b & 127;
        s = (t == 0) ? s0 : (t == 1) ? s1 : (t == 2) ? s2 : s3;
        d = (t == 0) ? d0 : (t == 1) ? d1 : (t == 2) ? d2 : d3;
        base = lb * 2048;
    } else if (b < 1024) { s = s4; d = d4; base = (b - 512) * 2048; }
    else                 { s = s5; d = d5; base = (b - 1024) * 2048; }
    int i = base + threadIdx.x * 8;
    float4 a = *(const float4*)&s[i];
    float4 c = *(const float4*)&s[i + 4];
    u16x8 o;
    o[0] = f2bf(a.x); o[1] = f2bf(a.y); o[2] = f2bf(a.z); o[3] = f2bf(a.w);
    o[4] = f2bf(c.x); o[5] = f2bf(c.y); o[6] = f2bf(c.z); o[7] = f2bf(c.w);
    *(u16x8*)&d[i] = o;
}

// ---------------------------------------------------------------------------
// bias^T[j][i] = alpha*softmax_j(relu(E E^T))[i][j] + beta*lap[i][j] + mask
// TRANSPOSED output so flash_attn can float4-load along the q-row axis.
// ---------------------------------------------------------------------------
__global__ __launch_bounds__(256)
void bias_kernel(const float* __restrict__ E, const float* __restrict__ lap,
                 const float* __restrict__ alpha_p, const float* __restrict__ beta_p,
                 float* __restrict__ biasout)
{
    __shared__ float wred[8];
    int tid = threadIdx.x;
    int i = blockIdx.x;
    int lane = tid & 63, wave = tid >> 6;
    int j0 = tid, j1 = tid + 256;
    float s0 = 0.f, s1 = 0.f;
#pragma unroll
    for (int t4 = 0; t4 < 16; ++t4) {
        float4 a  = *(const float4*)&E[i * 64 + t4 * 4];
        float4 e0 = *(const float4*)&E[j0 * 64 + t4 * 4];
        float4 e1 = *(const float4*)&E[j1 * 64 + t4 * 4];
        s0 += a.x * e0.x + a.y * e0.y + a.z * e0.z + a.w * e0.w;
        s1 += a.x * e1.x + a.y * e1.y + a.z * e1.z + a.w * e1.w;
    }
    s0 = fmaxf(s0, 0.f); s1 = fmaxf(s1, 0.f);
    float m = fmaxf(s0, s1);
#pragma unroll
    for (int o = 32; o > 0; o >>= 1) m = fmaxf(m, __shfl_xor(m, o));
    if (lane == 0) wred[wave] = m;
    __syncthreads();
    m = fmaxf(fmaxf(wred[0], wred[1]), fmaxf(wred[2], wred[3]));
    float e0v = __expf(s0 - m), e1v = __expf(s1 - m);
    float sum = e0v + e1v;
#pragma unroll
    for (int o = 32; o > 0; o >>= 1) sum += __shfl_xor(sum, o);
    if (lane == 0) wred[4 + wave] = sum;
    __syncthreads();
    float inv = 1.f / (wred[4] + wred[5] + wred[6] + wred[7]);
    float alpha = alpha_p[0], beta = beta_p[0];
    float lv0 = lap[i * 512 + j0];
    float lv1 = lap[i * 512 + j1];
    // transposed store: biasT[key][query]
    biasout[j0 * 512 + i] = alpha * (e0v * inv) + beta * lv0 + (lv0 != 0.f ? 0.f : -1e9f);
    biasout[j1 * 512 + i] = alpha * (e1v * inv) + beta * lv1 + (lv1 != 0.f ? 0.f : -1e9f);
}

// ---------------------------------------------------------------------------
// LayerNorm D=512, fp32 in, bf16 out
// ---------------------------------------------------------------------------
__global__ __launch_bounds__(256)
void ln_kernel(const float* __restrict__ X, const float* __restrict__ G,
               const float* __restrict__ Bb, u16* __restrict__ Y)
{
    int row = blockIdx.x * 4 + (threadIdx.x >> 6);
    int lane = threadIdx.x & 63;
    const float* xr = X + (size_t)row * 512 + lane * 8;
    float4 a = *(const float4*)xr;
    float4 b = *(const float4*)(xr + 4);
    float v[8] = {a.x, a.y, a.z, a.w, b.x, b.y, b.z, b.w};
    float s = 0.f, ss = 0.f;
#pragma unroll
    for (int i = 0; i < 8; i++) { s += v[i]; ss += v[i] * v[i]; }
#pragma unroll
    for (int o = 32; o > 0; o >>= 1) { s += __shfl_xor(s, o); ss += __shfl_xor(ss, o); }
    float mu = s * (1.f / 512.f);
    float var = ss * (1.f / 512.f) - mu * mu;
    float rstd = rsqrtf(var + 1e-5f);
    float4 g0 = *(const float4*)&G[lane * 8];
    float4 g1 = *(const float4*)&G[lane * 8 + 4];
    float4 b0 = *(const float4*)&Bb[lane * 8];
    float4 b1 = *(const float4*)&Bb[lane * 8 + 4];
    float gv[8] = {g0.x, g0.y, g0.z, g0.w, g1.x, g1.y, g1.z, g1.w};
    float bv[8] = {b0.x, b0.y, b0.z, b0.w, b1.x, b1.y, b1.z, b1.w};
    u16x8 out;
#pragma unroll
    for (int i = 0; i < 8; i++) out[i] = f2bf((v[i] - mu) * rstd * gv[i] + bv[i]);
    *(u16x8*)&Y[(size_t)row * 512 + lane * 8] = out;
}

// ---------------------------------------------------------------------------
// LDS GEMM (m97 pattern), 128x128 tile, XCD-swizzled, bf16 out (mode 0/1).
// Epilogue staged through LDS (stride 136) -> coalesced u16x8 global stores.
// ---------------------------------------------------------------------------
__global__ __launch_bounds__(256)
void gemm_bt(const u16* __restrict__ A, const u16* __restrict__ W,
             const float* __restrict__ bias,
             u16* __restrict__ Cb, int M, int Kd, int Nout, int mode)
{
    __shared__ __align__(16) char smem[128 * 136 * 2];   // 34 KB (>= lA+lB 16 KB)
    u16* lA = (u16*)smem;
    u16* lB = lA + 128 * 32;
    int tid = threadIdx.x;
    int lane = tid & 63, wave = tid >> 6;
    int wm = wave >> 1, wn = wave & 1;
    int bid = blockIdx.y * gridDim.x + blockIdx.x;
    int per = (gridDim.x * gridDim.y) >> 3;
    int lb  = (bid & 7) * per + (bid >> 3);
    int bx = lb % gridDim.x, by = lb / gridDim.x;
    int row0 = by * 128, col0 = bx * 128;
    int rl = lane & 15, kq = lane >> 4;
    f32x4 acc[4][4];
#pragma unroll
    for (int i = 0; i < 4; i++)
#pragma unroll
        for (int j = 0; j < 4; j++) acc[i][j] = (f32x4){0.f, 0.f, 0.f, 0.f};

    int c0 = tid,       sr0 = c0 >> 2, sc0 = (c0 & 3) * 8;
    int c1 = 256 + tid, sr1 = c1 >> 2, sc1 = (c1 & 3) * 8;
    const u16* Abase = A + (size_t)row0 * Kd;
    const u16* Wbase = W + (size_t)col0 * Kd;

    for (int k0 = 0; k0 < Kd; k0 += 32) {
        GL16(Abase + (size_t)sr0 * Kd + k0 + sc0, &lA[c0 * 8]);
        GL16(Abase + (size_t)sr1 * Kd + k0 + sc1, &lA[c1 * 8]);
        GL16(Wbase + (size_t)sr0 * Kd + k0 + sc0, &lB[c0 * 8]);
        GL16(Wbase + (size_t)sr1 * Kd + k0 + sc1, &lB[c1 * 8]);
        __syncthreads();
        bf16x8 af[4], bf[4];
#pragma unroll
        for (int i = 0; i < 4; i++) af[i] = *(const bf16x8*)&lA[(wm * 64 + i * 16 + rl) * 32 + kq * 8];
#pragma unroll
        for (int j = 0; j < 4; j++) bf[j] = *(const bf16x8*)&lB[(wn * 64 + j * 16 + rl) * 32 + kq * 8];
#pragma unroll
        for (int i = 0; i < 4; i++)
#pragma unroll
            for (int j = 0; j < 4; j++)
                acc[i][j] = __builtin_amdgcn_mfma_f32_16x16x32_bf16(af[i], bf[j], acc[i][j], 0, 0, 0);
        __syncthreads();
    }
    // epilogue: stage bf16 tile in LDS, then coalesced stores
    u16* lC = (u16*)smem;
#pragma unroll
    for (int j = 0; j < 4; j++) {
        int col = wn * 64 + j * 16 + rl;
        float bsv = bias[col0 + col];
#pragma unroll
        for (int i = 0; i < 4; i++) {
            int rb = wm * 64 + i * 16 + kq * 4;
#pragma unroll
            for (int r = 0; r < 4; r++) {
                float vo = acc[i][j][r] + bsv;
                if (mode == 1) vo = fmaxf(vo, 0.f);
                lC[(rb + r) * 136 + col] = f2bf(vo);
            }
        }
    }
    __syncthreads();
#pragma unroll
    for (int rep = 0; rep < 8; rep++) {
        int row = rep * 16 + (tid >> 4);
        int col8 = (tid & 15) * 8;
        *(u16x8*)&Cb[(size_t)(row0 + row) * Nout + col0 + col8] = *(const u16x8*)&lC[row * 136 + col8];
    }
}

// ---------------------------------------------------------------------------
// 128x128-tile LDS GEMM, fp32 out with residual, direct-scatter epilogue
// ---------------------------------------------------------------------------
__global__ __launch_bounds__(256)
void gemm128_res(const u16* __restrict__ A, const u16* __restrict__ W,
                 const float* __restrict__ bias, const float* __restrict__ resid,
                 float* __restrict__ Cf, int M, int Kd, int Nout)
{
    __shared__ __align__(16) u16 lA[128 * 32];
    __shared__ __align__(16) u16 lB[128 * 32];
    int tid = threadIdx.x;
    int lane = tid & 63, wave = tid >> 6;
    int wm = wave >> 1, wn = wave & 1;
    int bid = blockIdx.y * gridDim.x + blockIdx.x;
    int per = (gridDim.x * gridDim.y) >> 3;
    int lb  = (bid & 7) * per + (bid >> 3);
    int bx = lb % gridDim.x, by = lb / gridDim.x;
    int row0 = by * 128, col0 = bx * 128;
    int rl = lane & 15, kq = lane >> 4;
    f32x4 acc[4][4];
#pragma unroll
    for (int i = 0; i < 4; i++)
#pragma unroll
        for (int j = 0; j < 4; j++) acc[i][j] = (f32x4){0.f, 0.f, 0.f, 0.f};

    int c0 = tid,       sr0 = c0 >> 2, sc0 = (c0 & 3) * 8;
    int c1 = 256 + tid, sr1 = c1 >> 2, sc1 = (c1 & 3) * 8;
    const u16* Abase = A + (size_t)row0 * Kd;
    const u16* Wbase = W + (size_t)col0 * Kd;

    for (int k0 = 0; k0 < Kd; k0 += 32) {
        GL16(Abase + (size_t)sr0 * Kd + k0 + sc0, &lA[c0 * 8]);
        GL16(Abase + (size_t)sr1 * Kd + k0 + sc1, &lA[c1 * 8]);
        GL16(Wbase + (size_t)sr0 * Kd + k0 + sc0, &lB[c0 * 8]);
        GL16(Wbase + (size_t)sr1 * Kd + k0 + sc1, &lB[c1 * 8]);
        __syncthreads();
        bf16x8 af4[4], bf[4];
#pragma unroll
        for (int i = 0; i < 4; i++) af4[i] = *(const bf16x8*)&lA[(wm * 64 + i * 16 + rl) * 32 + kq * 8];
#pragma unroll
        for (int j = 0; j < 4; j++) bf[j] = *(const bf16x8*)&lB[(wn * 64 + j * 16 + rl) * 32 + kq * 8];
#pragma unroll
        for (int i = 0; i < 4; i++)
#pragma unroll
            for (int j = 0; j < 4; j++)
                acc[i][j] = __builtin_amdgcn_mfma_f32_16x16x32_bf16(af4[i], bf[j], acc[i][j], 0, 0, 0);
        __syncthreads();
    }
    // direct f32 epilogue: per quarter-wave a 64B contiguous run -> coalesced
#pragma unroll
    for (int j = 0; j < 4; j++) {
        int col = col0 + wn * 64 + j * 16 + rl;
        float bsv = bias[col];
#pragma unroll
        for (int i = 0; i < 4; i++) {
            int rb = row0 + wm * 64 + i * 16 + kq * 4;
#pragma unroll
            for (int r = 0; r < 4; r++) {
                size_t idx = (size_t)(rb + r) * Nout + col;
                Cf[idx] = acc[i][j][r] + bsv + resid[idx];
            }
        }
    }
}

// ---------------------------------------------------------------------------
// fused QKV, XCD-swizzled, LDS-staged epilogue
// ---------------------------------------------------------------------------
__global__ __launch_bounds__(256)
void gemm_qkv(const u16* __restrict__ A,
              const u16* __restrict__ W0, const u16* __restrict__ W1, const u16* __restrict__ W2,
              const float* __restrict__ b0, const float* __restrict__ b1, const float* __restrict__ b2,
              u16* __restrict__ C0, u16* __restrict__ C1, u16* __restrict__ C2)
{
    __shared__ __align__(16) char smem[128 * 136 * 2];   // 34 KB
    u16* lA = (u16*)smem;
    u16* lB = lA + 128 * 32;
    const int Kd = 512, Nout = 512;
    int bid = blockIdx.y * gridDim.x + blockIdx.x;
    int per = (gridDim.x * gridDim.y) >> 3;       // 192
    int lb  = (bid & 7) * per + (bid >> 3);
    int rest = lb % 12, by = lb / 12;
    int sel = rest >> 2;
    const u16* W = (sel == 0) ? W0 : (sel == 1) ? W1 : W2;
    const float* bias = (sel == 0) ? b0 : (sel == 1) ? b1 : b2;
    u16* Cb = (sel == 0) ? C0 : (sel == 1) ? C1 : C2;
    int tid = threadIdx.x;
    int lane = tid & 63, wave = tid >> 6;
    int wm = wave >> 1, wn = wave & 1;
    int row0 = by * 128, col0 = (rest & 3) * 128;
    int rl = lane & 15, kq = lane >> 4;
    f32x4 acc[4][4];
#pragma unroll
    for (int i = 0; i < 4; i++)
#pragma unroll
        for (int j = 0; j < 4; j++) acc[i][j] = (f32x4){0.f, 0.f, 0.f, 0.f};
    int c0 = tid,       sr0 = c0 >> 2, sc0 = (c0 & 3) * 8;
    int c1 = 256 + tid, sr1 = c1 >> 2, sc1 = (c1 & 3) * 8;
    const u16* Abase = A + (size_t)row0 * Kd;
    const u16* Wbase = W + (size_t)col0 * Kd;
    for (int k0 = 0; k0 < Kd; k0 += 32) {
        GL16(Abase + (size_t)sr0 * Kd + k0 + sc0, &lA[c0 * 8]);
        GL16(Abase + (size_t)sr1 * Kd + k0 + sc1, &lA[c1 * 8]);
        GL16(Wbase + (size_t)sr0 * Kd + k0 + sc0, &lB[c0 * 8]);
        GL16(Wbase + (size_t)sr1 * Kd + k0 + sc1, &lB[c1 * 8]);
        __syncthreads();
        bf16x8 af[4], bf[4];
#pragma unroll
        for (int i = 0; i < 4; i++) af[i] = *(const bf16x8*)&lA[(wm * 64 + i * 16 + rl) * 32 + kq * 8];
#pragma unroll
        for (int j = 0; j < 4; j++) bf[j] = *(const bf16x8*)&lB[(wn * 64 + j * 16 + rl) * 32 + kq * 8];
#pragma unroll
        for (int i = 0; i < 4; i++)
#pragma unroll
            for (int j = 0; j < 4; j++)
                acc[i][j] = __builtin_amdgcn_mfma_f32_16x16x32_bf16(af[i], bf[j], acc[i][j], 0, 0, 0);
        __syncthreads();
    }
    u16* lC = (u16*)smem;
#pragma unroll
    for (int j = 0; j < 4; j++) {
        int col = wn * 64 + j * 16 + rl;
        float bsv = bias[col0 + col];
#pragma unroll
        for (int i = 0; i < 4; i++) {
            int rb = wm * 64 + i * 16 + kq * 4;
#pragma unroll
            for (int r = 0; r < 4; r++)
                lC[(rb + r) * 136 + col] = f2bf(acc[i][j][r] + bsv);
        }
    }
    __syncthreads();
#pragma unroll
    for (int rep = 0; rep < 8; rep++) {
        int row = rep * 16 + (tid >> 4);
        int col8 = (tid & 15) * 8;
        *(u16x8*)&Cb[(size_t)(row0 + row) * Nout + col0 + col8] = *(const u16x8*)&lC[row * 136 + col8];
    }
}

// ---------------------------------------------------------------------------
// flash attention v7 = v6 with lVt reverted to baseline PADDED 64x68 layout.
// v6 post-mortem: 128-VGPR clamp (no spill) but 21us slower than baseline ->
// ILP-starved scheduling from swizzle/bias addr temps. Padded lVt reads are
// stride-68-dword (2-way bank aliasing = free, m136); only K/Q stride-64 was
// the real 16-way conflict, and its XOR swizzle stays. Register diet drops
// natural demand back to the baseline ~124 class -> clamp inactive.
// LDS: lPK 34816 + lQ/lVt union 17408 + red 1024 + 4x512 = 55296 B, 2 blk/CU.
// ---------------------------------------------------------------------------
__global__ __launch_bounds__(256, 2)
void flash_attn(const u16* __restrict__ Q, const u16* __restrict__ Km,
                const u16* __restrict__ V, const float* __restrict__ biasT,
                u16* __restrict__ O)
{
    __shared__ __align__(16) char smem[55296];
    u16* lPK      = (u16*)smem;                      // K-stage 128x64 (swz) / P 128x136 / O-stage
    u16* lQ       = (u16*)(smem + 34816);            // Q-stage 128x64 (swz), union with lVt
    unsigned* lVt = (unsigned*)(smem + 34816);       // V^T 64 x 68 dwords (padded, baseline)
    float* red     = (float*)(smem + 52224);         // 256 f
    float* m_s     = red + 256;                      // 128 f
    float* mnew_s  = m_s + 128;                      // 128 f
    float* alpha_s = mnew_s + 128;                   // 128 f
    float* l_s     = alpha_s + 128;                  // 128 f  -> total 55296

    int tid = threadIdx.x, lane = tid & 63, wave = tid >> 6;
    int wm = wave >> 1, wn = wave & 1;
    int rl = lane & 15, kq = lane >> 4;
    int qt = blockIdx.x, h = blockIdx.y, bt = blockIdx.z;
    int qg0 = qt * 128;
    size_t hb = (size_t)bt * (512 * 512) + h * 64;
    const u16* Qbase = Q + hb + (size_t)qg0 * 512;
    const u16* Kb0   = Km + hb;
    const u16* Vb0   = V + hb;

    // stage Q: linear LDS dest, inverse-swizzled global source (rule #21)
#pragma unroll
    for (int rep = 0; rep < 4; ++rep) {
        int c = rep * 256 + tid;
        int qr = c >> 3, d0 = (((c & 7) ^ (qr & 7)) * 8);
        GL16(Qbase + (size_t)qr * 512 + d0, &lQ[c * 8]);
    }
    if (tid < 128) { m_s[tid] = -3.0e38f; l_s[tid] = 0.f; }
    __syncthreads();

    bf16x8 af[4][2];
#pragma unroll
    for (int i = 0; i < 4; i++) {
        int row = wm * 64 + i * 16 + rl;
#pragma unroll
        for (int s = 0; s < 2; s++) {
            int sl = (s * 4 + kq) ^ (row & 7);
            af[i][s] = *(const bf16x8*)&lQ[row * 64 + sl * 8];
        }
    }

    f32x4 o[4][2];
#pragma unroll
    for (int i = 0; i < 4; i++)
#pragma unroll
        for (int jj = 0; jj < 2; jj++) o[i][jj] = (f32x4){0.f, 0.f, 0.f, 0.f};

    for (int t = 0; t < 4; ++t) {
        int kv0 = t * 128;
        __syncthreads();                              // barrier 1: buffers reusable
        const u16* Kbase = Kb0 + (size_t)kv0 * 512;
#pragma unroll
        for (int rep = 0; rep < 4; ++rep) {
            int c = rep * 256 + tid;
            int kv = c >> 3, d0 = (((c & 7) ^ (kv & 7)) * 8);
            GL16(Kbase + (size_t)kv * 512 + d0, &lPK[c * 8]);
        }
        const u16* Vbase = Vb0 + (size_t)kv0 * 512;
#pragma unroll
        for (int rep = 0; rep < 2; ++rep) {
            int idx = rep * 256 + tid;
            int p = idx & 63, e0 = (idx >> 6) * 8;
            const u16* vp0 = Vbase + (size_t)(2 * p) * 512 + e0;
            u16x8 v0 = *(const u16x8*)vp0;
            u16x8 v1 = *(const u16x8*)(vp0 + 512);
#pragma unroll
            for (int u = 0; u < 8; ++u)
                lVt[(e0 + u) * 68 + p] = (unsigned)v0[u] | ((unsigned)v1[u] << 16);
        }
        __syncthreads();                              // barrier 2: tiles ready

        f32x4 acc[4][4];
#pragma unroll
        for (int j = 0; j < 4; ++j) {
            int row = wn * 64 + j * 16 + rl;
            int sl0 = kq ^ (row & 7), sl1 = (4 + kq) ^ (row & 7);
            bf16x8 bk0 = *(const bf16x8*)&lPK[row * 64 + sl0 * 8];
            bf16x8 bk1 = *(const bf16x8*)&lPK[row * 64 + sl1 * 8];
#pragma unroll
            for (int i = 0; i < 4; ++i) {
                acc[i][j] = __builtin_amdgcn_mfma_f32_16x16x32_bf16(af[i][0], bk0,
                            (f32x4){0.f, 0.f, 0.f, 0.f}, 0, 0, 0);
                acc[i][j] = __builtin_amdgcn_mfma_f32_16x16x32_bf16(af[i][1], bk1, acc[i][j], 0, 0, 0);
            }
        }
        // bias add: transposed table -> one float4 per (i,j)
#pragma unroll
        for (int j = 0; j < 4; ++j) {
            int colg = kv0 + wn * 64 + j * 16 + rl;
            const float* bp = biasT + (size_t)colg * 512 + qg0;
#pragma unroll
            for (int i = 0; i < 4; ++i) {
                float4 bv = *(const float4*)&bp[wm * 64 + i * 16 + kq * 4];
                float bvr[4] = {bv.x, bv.y, bv.z, bv.w};
#pragma unroll
                for (int r = 0; r < 4; ++r)
                    acc[i][j][r] = acc[i][j][r] * 0.125f + bvr[r];
            }
        }
        // row max (this wn half) -> red
#pragma unroll
        for (int i = 0; i < 4; ++i) {
            float mx[4];
#pragma unroll
            for (int r = 0; r < 4; ++r) {
                mx[r] = fmaxf(fmaxf(acc[i][0][r], acc[i][1][r]), fmaxf(acc[i][2][r], acc[i][3][r]));
#pragma unroll
                for (int off = 8; off > 0; off >>= 1) mx[r] = fmaxf(mx[r], __shfl_xor(mx[r], off));
            }
            if (rl == 0) {
                int rb = wm * 64 + i * 16 + kq * 4;
#pragma unroll
                for (int r = 0; r < 4; ++r) red[wn * 128 + rb + r] = mx[r];
            }
        }
        __syncthreads();                              // barrier 3: max exchange
        if (tid < 128) {
            float pm = fmaxf(red[tid], red[128 + tid]);
            float mo = m_s[tid];
            float mn = fmaxf(mo, pm);
            m_s[tid] = mn; mnew_s[tid] = mn;
            alpha_s[tid] = __expf(mo - mn);
        }
        __syncthreads();                              // barrier 4: m/alpha ready

#pragma unroll
        for (int i = 0; i < 4; ++i) {
            int rb = wm * 64 + i * 16 + kq * 4;
            float mn[4], al[4], sm[4];
#pragma unroll
            for (int r = 0; r < 4; ++r) { mn[r] = mnew_s[rb + r]; al[r] = alpha_s[rb + r]; sm[r] = 0.f; }
#pragma unroll
            for (int j = 0; j < 4; ++j) {
                int col = wn * 64 + j * 16 + rl;
#pragma unroll
                for (int r = 0; r < 4; ++r) {
                    float p = __expf(acc[i][j][r] - mn[r]);
                    sm[r] += p;
                    lPK[(rb + r) * 136 + col] = f2bf(p);
                }
            }
#pragma unroll
            for (int jj = 0; jj < 2; ++jj)
#pragma unroll
                for (int r = 0; r < 4; ++r) o[i][jj][r] *= al[r];
#pragma unroll
            for (int r = 0; r < 4; ++r) {
#pragma unroll
                for (int off = 8; off > 0; off >>= 1) sm[r] += __shfl_xor(sm[r], off);
            }
            if (rl == 0) {
#pragma unroll
                for (int r = 0; r < 4; ++r) red[wn * 128 + rb + r] = sm[r];
            }
        }
        __syncthreads();                              // barrier 5: sum exchange + P visible
        if (tid < 128) l_s[tid] = l_s[tid] * alpha_s[tid] + red[tid] + red[128 + tid];

        // PV
#pragma unroll
        for (int ks = 0; ks < 4; ++ks) {
            bf16x8 aP[4], bV[2];
#pragma unroll
            for (int i = 0; i < 4; ++i)
                aP[i] = *(const bf16x8*)&lPK[(wm * 64 + i * 16 + rl) * 136 + ks * 32 + kq * 8];
#pragma unroll
            for (int jj = 0; jj < 2; ++jj)
                bV[jj] = *(const bf16x8*)&lVt[(wn * 32 + jj * 16 + rl) * 68 + ks * 16 + kq * 4];
#pragma unroll
            for (int i = 0; i < 4; ++i)
#pragma unroll
                for (int jj = 0; jj < 2; ++jj)
                    o[i][jj] = __builtin_amdgcn_mfma_f32_16x16x32_bf16(aP[i], bV[jj], o[i][jj], 0, 0, 0);
        }
    }
    __syncthreads();

    // epilogue: stage O tile (128x64 bf16) in lPK, then coalesced stores
#pragma unroll
    for (int i = 0; i < 4; ++i) {
        int rb = wm * 64 + i * 16 + kq * 4;
        float il[4];
#pragma unroll
        for (int r = 0; r < 4; ++r) il[r] = 1.f / l_s[rb + r];
#pragma unroll
        for (int jj = 0; jj < 2; ++jj) {
            int e = wn * 32 + jj * 16 + rl;
#pragma unroll
            for (int r = 0; r < 4; ++r)
                lPK[(rb + r) * 136 + e] = f2bf(o[i][jj][r] * il[r]);
        }
    }
    __syncthreads();
    u16* Ob = O + hb + (size_t)qg0 * 512;
#pragma unroll
    for (int rep = 0; rep < 4; ++rep) {
        int row = rep * 32 + (tid >> 3);
        int col8 = (tid & 7) * 8;
        *(u16x8*)&Ob[(size_t)row * 512 + col8] = *(const u16x8*)&lPK[row * 136 + col8];
    }
}

// ---------------------------------------------------------------------------
extern "C" void kernel_launch(void* const* d_in, const int* in_sizes, int n_in,
                              void* d_out, int out_size, void* d_ws, size_t ws_size,
                              hipStream_t stream)
{
    const float* x     = (const float*)d_in[0];
    const float* lap   = (const float*)d_in[1];
    const float* emb   = (const float*)d_in[2];
    const float* Wq    = (const float*)d_in[3];
    const float* bq    = (const float*)d_in[4];
    const float* Wk    = (const float*)d_in[5];
    const float* bk    = (const float*)d_in[6];
    const float* Wv    = (const float*)d_in[7];
    const float* bvv   = (const float*)d_in[8];
    const float* g1    = (const float*)d_in[9];
    const float* bb1   = (const float*)d_in[10];
    const float* g2    = (const float*)d_in[11];
    const float* bb2   = (const float*)d_in[12];
    const float* alpha = (const float*)d_in[13];
    const float* beta  = (const float*)d_in[14];
    const float* Wo    = (const float*)d_in[15];
    const float* bo    = (const float*)d_in[16];
    const float* W1    = (const float*)d_in[17];
    const float* b1    = (const float*)d_in[18];
    const float* W2    = (const float*)d_in[19];
    const float* b2    = (const float*)d_in[20];
    float* out = (float*)d_out;

    const size_t SZ = (size_t)4 * 8 * 512 * 512;
    char* w = (char*)d_ws;
    float* bias = (float*)w;  w += (size_t)512 * 512 * 4;   // holds bias^T now
    u16* wqb = (u16*)w; w += (size_t)512 * 512 * 2;
    u16* wkb = (u16*)w; w += (size_t)512 * 512 * 2;
    u16* wvb = (u16*)w; w += (size_t)512 * 512 * 2;
    u16* wob = (u16*)w; w += (size_t)512 * 512 * 2;
    u16* w1b = (u16*)w; w += (size_t)2048 * 512 * 2;
    u16* w2b = (u16*)w; w += (size_t)512 * 2048 * 2;
    u16* xnb = (u16*)w; w += SZ * 2;   // LN1 out; reused as attention output
    u16* qb  = (u16*)w; w += SZ * 2;   // Q; reused as LN2 out
    u16* kb  = (u16*)w; w += SZ * 2;
    u16* vb  = (u16*)w; w += SZ * 2;
    u16* hb  = (u16*)w; w += (size_t)16384 * 2048 * 2;
    float* x1 = out;

    const int M = 16384;
    cvt6_kernel<<<1536, 256, 0, stream>>>(Wq, Wk, Wv, Wo, W1, W2,
                                          wqb, wkb, wvb, wob, w1b, w2b);
    bias_kernel<<<512, 256, 0, stream>>>(emb, lap, alpha, beta, bias);
    ln_kernel<<<M / 4, 256, 0, stream>>>(x, g1, bb1, xnb);
    gemm_qkv<<<dim3(12, 128), 256, 0, stream>>>(xnb, wqb, wkb, wvb, bq, bk, bvv, qb, kb, vb);
    flash_attn<<<dim3(4, 8, 32), 256, 0, stream>>>(qb, kb, vb, bias, xnb);
    gemm128_res<<<dim3(4, 128), 256, 0, stream>>>(xnb, wob, bo, x, x1, M, 512, 512);
    ln_kernel<<<M / 4, 256, 0, stream>>>(x1, g2, bb2, qb);
    gemm_bt<<<dim3(16, 128), 256, 0, stream>>>(qb, w1b, b1, hb, M, 512, 2048, 1);
    gemm128_res<<<dim3(4, 128), 256, 0, stream>>>(hb, w2b, b2, x1, out, M, 2048, 512);
}